// Round 14
// baseline (343.171 us; speedup 1.0000x reference)
//
#include <hip/hip_runtime.h>
#include <cstdint>
#include <cstddef>

#define N_NODES_C 200000
#define N_EDGES_C 600000
#define NUM_GRAPHS_C 20000

constexpr float NEG_SLOPE = 0.2f;
constexpr float LN_EPS = 1e-5f;

typedef __attribute__((ext_vector_type(8))) short bf16x8;
typedef __attribute__((ext_vector_type(4))) float f32x4;

// bf16 helpers (RNE)
static __device__ __forceinline__ unsigned short f2bf(float f) {
  unsigned u = __float_as_uint(f);
  u = (u + 0x7fffu + ((u >> 16) & 1u)) >> 16;
  return (unsigned short)u;
}
static __device__ __forceinline__ float bf2f(unsigned short s) {
  return __uint_as_float(((unsigned)s) << 16);
}

// ---------------- CSR build ----------------

__global__ __launch_bounds__(256) void count_deg_kernel(const int* __restrict__ dst,
                                                        int* __restrict__ deg, int E) {
  int e = blockIdx.x * 256 + threadIdx.x;
  if (e < E) atomicAdd(&deg[dst[e]], 1);
}

__global__ __launch_bounds__(256) void scan_kernel(const int* __restrict__ in,
                                                   int* __restrict__ out,
                                                   int* __restrict__ bsums, int n) {
  __shared__ int ss[256];
  int t = threadIdx.x;
  int base = blockIdx.x * 1024 + t * 4;
  int v[4];
  int s = 0;
#pragma unroll
  for (int j = 0; j < 4; ++j) {
    v[j] = (base + j < n) ? in[base + j] : 0;
    s += v[j];
  }
  ss[t] = s;
  __syncthreads();
  for (int off = 1; off < 256; off <<= 1) {
    int x = (t >= off) ? ss[t - off] : 0;
    __syncthreads();
    ss[t] += x;
    __syncthreads();
  }
  int incl = ss[t];
  int excl = incl - s;
  if (bsums != nullptr && t == 255) bsums[blockIdx.x] = incl;
  int run = excl;
#pragma unroll
  for (int j = 0; j < 4; ++j) {
    if (base + j < n) out[base + j] = run;
    run += v[j];
  }
}

__global__ __launch_bounds__(256) void scan_addoff_kernel(int* __restrict__ data,
                                                          const int* __restrict__ boff,
                                                          int n, int total) {
  int base = blockIdx.x * 1024 + threadIdx.x * 4;
  int add = boff[blockIdx.x];
#pragma unroll
  for (int j = 0; j < 4; ++j) {
    if (base + j < n) data[base + j] += add;
  }
  if (blockIdx.x == 0 && threadIdx.x == 0) data[n] = total;
}

// also records eslot[e] = CSR slot of edge e (fixes the round-7 index-space bug
// by construction: scores can be written in CSR slot order later)
__global__ __launch_bounds__(256) void fill_csr_kernel(const int* __restrict__ src,
                                                       const int* __restrict__ dst,
                                                       const int* __restrict__ row_ptr,
                                                       int* __restrict__ cursor,
                                                       int* __restrict__ col,
                                                       int* __restrict__ eslot, int E) {
  int e = blockIdx.x * 256 + threadIdx.x;
  if (e < E) {
    int d = dst[e];
    int p = atomicAdd(&cursor[d], 1);
    int slot = row_ptr[d] + p;
    col[slot] = src[e];
    eslot[e] = slot;
  }
}

// ---------------- graph_ptr from sorted batch ----------------

__global__ __launch_bounds__(256) void graph_ptr_kernel(const int* __restrict__ batch,
                                                        int* __restrict__ gp, int n,
                                                        int G) {
  int i = blockIdx.x * 256 + threadIdx.x;
  if (i < n) {
    int prev = (i == 0) ? -1 : batch[i - 1];
    int cur = batch[i];
#pragma unroll 1
    for (int g = prev + 1; g <= cur; ++g) gp[g] = i;
  } else if (i == n) {
    int last = batch[n - 1];
#pragma unroll 1
    for (int g = last + 1; g <= G; ++g) gp[g] = n;
  }
}

// ---------------- W prep: fp32 [k][n] -> bf16 W^T padded [n][136] ----------

__global__ __launch_bounds__(256) void wprep_kernel(const float* __restrict__ W,
                                                    unsigned short* __restrict__ Wtp) {
  int idx = blockIdx.x * 256 + threadIdx.x;
  if (idx >= 128 * 136) return;
  int n = idx / 136, k = idx % 136;
  Wtp[idx] = (k < 128) ? f2bf(W[(size_t)k * 128 + n]) : (unsigned short)0;
}

// ---------------- MFMA GEMM + att-score epilogue (unchanged, verified) ------

template <int H, bool A_BF16>
__global__ __launch_bounds__(256) void gemm_att_mfma(
    const void* __restrict__ Av, const unsigned short* __restrict__ Wtp,
    const float* __restrict__ att_src, const float* __restrict__ att_dst,
    unsigned short* __restrict__ Cbf, float* __restrict__ asrc,
    float* __restrict__ adst) {
  __shared__ __align__(16) unsigned short Alds[64 * 136];
  __shared__ __align__(16) unsigned short Wlds[128 * 136];
  int tid = threadIdx.x;
  int lane = tid & 63;
  int wave = tid >> 6;
  int row0 = blockIdx.x * 64;

#pragma unroll
  for (int i = 0; i < 9; ++i) {
    int ch = tid + i * 256;
    if (ch < 2176) *(bf16x8*)&Wlds[ch * 8] = *(const bf16x8*)&Wtp[(size_t)ch * 8];
  }
#pragma unroll
  for (int i = 0; i < 4; ++i) {
    int ch = tid + i * 256;
    int r = ch >> 4, c = ch & 15;
    if constexpr (A_BF16) {
      bf16x8 v = *(const bf16x8*)((const unsigned short*)Av +
                                  (size_t)(row0 + r) * 128 + c * 8);
      *(bf16x8*)&Alds[r * 136 + c * 8] = v;
    } else {
      const float* A = (const float*)Av;
      float4 v0 = *(const float4*)(A + (size_t)(row0 + r) * 128 + c * 8);
      float4 v1 = *(const float4*)(A + (size_t)(row0 + r) * 128 + c * 8 + 4);
      unsigned short tmp[8] = {f2bf(v0.x), f2bf(v0.y), f2bf(v0.z), f2bf(v0.w),
                               f2bf(v1.x), f2bf(v1.y), f2bf(v1.z), f2bf(v1.w)};
      *(bf16x8*)&Alds[r * 136 + c * 8] = *(bf16x8*)tmp;
    }
  }
  __syncthreads();

  int l15 = lane & 15;
  int lg = lane >> 4;
  int wr = wave * 16;

  f32x4 acc[8];
#pragma unroll
  for (int nt = 0; nt < 8; ++nt) acc[nt] = (f32x4){0.f, 0.f, 0.f, 0.f};

#pragma unroll
  for (int ks = 0; ks < 4; ++ks) {
    bf16x8 af = *(const bf16x8*)&Alds[(wr + l15) * 136 + ks * 32 + lg * 8];
#pragma unroll
    for (int nt = 0; nt < 8; ++nt) {
      bf16x8 bfr = *(const bf16x8*)&Wlds[(nt * 16 + l15) * 136 + ks * 32 + lg * 8];
      acc[nt] = __builtin_amdgcn_mfma_f32_16x16x32_bf16(af, bfr, acc[nt], 0, 0, 0);
    }
  }

  float vsv[8], vdv[8];
#pragma unroll
  for (int nt = 0; nt < 8; ++nt) {
    vsv[nt] = att_src[nt * 16 + l15];
    vdv[nt] = att_dst[nt * 16 + l15];
  }

#pragma unroll
  for (int r = 0; r < 4; ++r) {
    int row = row0 + wr + lg * 4 + r;
#pragma unroll
    for (int nt = 0; nt < 8; ++nt) {
      Cbf[(size_t)row * 128 + nt * 16 + l15] = f2bf(acc[nt][r]);
    }
    if constexpr (H == 4) {
      float ps[4], pd[4];
#pragma unroll
      for (int hd = 0; hd < 4; ++hd) {
        ps[hd] = acc[2 * hd][r] * vsv[2 * hd] + acc[2 * hd + 1][r] * vsv[2 * hd + 1];
        pd[hd] = acc[2 * hd][r] * vdv[2 * hd] + acc[2 * hd + 1][r] * vdv[2 * hd + 1];
#pragma unroll
        for (int off = 1; off < 16; off <<= 1) {
          ps[hd] += __shfl_xor(ps[hd], off, 64);
          pd[hd] += __shfl_xor(pd[hd], off, 64);
        }
      }
      if (l15 < 4) {
        float pss = (l15 == 0) ? ps[0] : (l15 == 1) ? ps[1] : (l15 == 2) ? ps[2] : ps[3];
        float pds = (l15 == 0) ? pd[0] : (l15 == 1) ? pd[1] : (l15 == 2) ? pd[2] : pd[3];
        asrc[(size_t)row * 4 + l15] = pss;
        adst[(size_t)row * 4 + l15] = pds;
      }
    } else {
      float ps = 0.f, pd = 0.f;
#pragma unroll
      for (int nt = 0; nt < 8; ++nt) {
        ps = fmaf(acc[nt][r], vsv[nt], ps);
        pd = fmaf(acc[nt][r], vdv[nt], pd);
      }
#pragma unroll
      for (int off = 1; off < 16; off <<= 1) {
        ps += __shfl_xor(ps, off, 64);
        pd += __shfl_xor(pd, off, 64);
      }
      if (l15 == 0) {
        asrc[row] = ps;
        adst[row] = pd;
      }
    }
  }
}

// ---------------- edge scores in CSR-slot order (no atomics) ----------------
// ev layout transposed [head][slot] (plane stride EP) so agg reads are
// 16-lane-uniform broadcast loads of 4 consecutive slots.

template <int H>
__global__ __launch_bounds__(256) void edge_score_kernel(
    const int* __restrict__ src, const int* __restrict__ dst,
    const int* __restrict__ eslot, const float* __restrict__ asrc,
    const float* __restrict__ adst, float* __restrict__ evt, int E, int EP) {
  int e = blockIdx.x * 256 + threadIdx.x;
  if (e >= E) return;
  int s = src[e], d = dst[e], slot = eslot[e];
  if constexpr (H == 4) {
    float4 a = *(const float4*)(asrc + (size_t)s * 4);
    float4 b = *(const float4*)(adst + (size_t)d * 4);
    float v[4] = {a.x + b.x, a.y + b.y, a.z + b.z, a.w + b.w};
#pragma unroll
    for (int k = 0; k < 4; ++k) {
      float x = v[k];
      x = (x > 0.f) ? x : NEG_SLOPE * x;
      evt[(size_t)k * EP + slot] = __expf(x);
    }
  } else {
    float x = asrc[s] + adst[d];
    x = (x > 0.f) ? x : NEG_SLOPE * x;
    evt[slot] = __expf(x);
  }
}

// ---------------- Pass B: TWO nodes/wave, precomputed ev, inline denom ------
// Inner loop per 4 edges per node: 4 uniform col loads + 4 uniform ev loads
// + 4 h-row gathers + unpack/fma/den — the redundant 64-lane exp chain and
// asrc gathers (round-13: 84% VALUBusy) are gone. All slot loads are
// in-bounds by CSR construction (e0A+tmax-1 < e1B <= E); masks applied after.

template <int H, bool RELU, bool LNOUT>
__global__ __launch_bounds__(256) void gat_agg4_kernel(
    const unsigned short* __restrict__ h, const float* __restrict__ asrc,
    const float* __restrict__ adst, const float* __restrict__ evt, int EP,
    const int* __restrict__ row_ptr, const int* __restrict__ col,
    const float* __restrict__ bias, const float* __restrict__ gamma,
    const float* __restrict__ beta, unsigned short* __restrict__ outbf, int n) {
  int wid = (blockIdx.x * 256 + threadIdx.x) >> 6;
  int lane = threadIdx.x & 63;
  int nodeA = wid * 2;
  int nodeB = nodeA + 1;
  if (nodeA >= n) return;
  bool hasB = nodeB < n;

  int e0A = row_ptr[nodeA];
  int e1A = row_ptr[nodeA + 1];
  int e1B = hasB ? row_ptr[nodeB + 1] : e1A;
  int e0B = e1A;
  int nedA = e1A - e0A;
  int nedB = e1B - e0B;

  int c0 = lane * 2;
  const int hd = (H == 1) ? 0 : (lane >> 4);
  const float* evh = evt + (size_t)hd * EP;

  // self-loop exp + denom init
  float adA = (H == 4) ? adst[(size_t)nodeA * 4 + hd] : adst[nodeA];
  float asA = (H == 4) ? asrc[(size_t)nodeA * 4 + hd] : asrc[nodeA];
  int nB = hasB ? nodeB : nodeA;
  float adB = (H == 4) ? adst[(size_t)nB * 4 + hd] : adst[nB];
  float asB = (H == 4) ? asrc[(size_t)nB * 4 + hd] : asrc[nB];

  float xA = asA + adA; xA = (xA > 0.f) ? xA : NEG_SLOPE * xA;
  float selfeA = __expf(xA);
  float xB = asB + adB; xB = (xB > 0.f) ? xB : NEG_SLOPE * xB;
  float selfeB = __expf(xB);

  float denA = selfeA;
  float denB = selfeB;

  float2 accA, accB;
  {
    unsigned ha = *(const unsigned*)(h + (size_t)nodeA * 128 + c0);
    unsigned hb = *(const unsigned*)(h + (size_t)nB * 128 + c0);
    accA.x = bf2f((unsigned short)(ha & 0xffffu)) * selfeA;
    accA.y = bf2f((unsigned short)(ha >> 16)) * selfeA;
    accB.x = bf2f((unsigned short)(hb & 0xffffu)) * selfeB;
    accB.y = bf2f((unsigned short)(hb >> 16)) * selfeB;
  }

  int tmax = (nedA > nedB) ? nedA : nedB;
#pragma unroll 1
  for (int t = 0; t < tmax; t += 4) {
    int sA4[4], sB4[4];
    float eA4[4], eB4[4];
#pragma unroll
    for (int i = 0; i < 4; ++i) {
      int e = t + i;
      bool vA = e < nedA;
      bool vB = hasB && e < nedB;
      int cA = col[e0A + e];            // in-bounds by construction
      int cB = col[e0B + e];
      float fA = evh[e0A + e];
      float fB = evh[e0B + e];
      sA4[i] = vA ? cA : nodeA;
      sB4[i] = vB ? cB : nodeA;
      eA4[i] = vA ? fA : 0.f;
      eB4[i] = vB ? fB : 0.f;
    }
    unsigned hA4[4], hB4[4];
#pragma unroll
    for (int i = 0; i < 4; ++i) {
      hA4[i] = *(const unsigned*)(h + (size_t)sA4[i] * 128 + c0);
      hB4[i] = *(const unsigned*)(h + (size_t)sB4[i] * 128 + c0);
    }
#pragma unroll
    for (int i = 0; i < 4; ++i) {
      denA += eA4[i];
      denB += eB4[i];
      accA.x = fmaf(bf2f((unsigned short)(hA4[i] & 0xffffu)), eA4[i], accA.x);
      accA.y = fmaf(bf2f((unsigned short)(hA4[i] >> 16)), eA4[i], accA.y);
      accB.x = fmaf(bf2f((unsigned short)(hB4[i] & 0xffffu)), eB4[i], accB.x);
      accB.y = fmaf(bf2f((unsigned short)(hB4[i] >> 16)), eB4[i], accB.y);
    }
  }

  float invA = 1.f / denA;
  float invB = 1.f / denB;

  float bx = bias[c0], by = bias[c0 + 1];
  accA.x = fmaf(accA.x, invA, bx);
  accA.y = fmaf(accA.y, invA, by);
  accB.x = fmaf(accB.x, invB, bx);
  accB.y = fmaf(accB.y, invB, by);
  if (RELU) {
    accA.x = fmaxf(accA.x, 0.f); accA.y = fmaxf(accA.y, 0.f);
    accB.x = fmaxf(accB.x, 0.f); accB.y = fmaxf(accB.y, 0.f);
  }

  if (!LNOUT) {
    unsigned pa = (unsigned)f2bf(accA.x) | ((unsigned)f2bf(accA.y) << 16);
    *(unsigned*)(outbf + (size_t)nodeA * 128 + c0) = pa;
    if (hasB) {
      unsigned pb = (unsigned)f2bf(accB.x) | ((unsigned)f2bf(accB.y) << 16);
      *(unsigned*)(outbf + (size_t)nodeB * 128 + c0) = pb;
    }
  } else {
    float sA = accA.x + accA.y;
    float sB = accB.x + accB.y;
#pragma unroll
    for (int off = 1; off < 64; off <<= 1) {
      sA += __shfl_xor(sA, off, 64);
      sB += __shfl_xor(sB, off, 64);
    }
    float muA = sA * (1.f / 128.f), muB = sB * (1.f / 128.f);
    float dxA = accA.x - muA, dyA = accA.y - muA;
    float dxB = accB.x - muB, dyB = accB.y - muB;
    float vA = dxA * dxA + dyA * dyA;
    float vB = dxB * dxB + dyB * dyB;
#pragma unroll
    for (int off = 1; off < 64; off <<= 1) {
      vA += __shfl_xor(vA, off, 64);
      vB += __shfl_xor(vB, off, 64);
    }
    float ivA = rsqrtf(vA * (1.f / 128.f) + LN_EPS);
    float ivB = rsqrtf(vB * (1.f / 128.f) + LN_EPS);
    float gx = gamma[c0], gy = gamma[c0 + 1];
    float ex = beta[c0], ey = beta[c0 + 1];
    float oxA = fmaf(dxA * ivA, gx, ex), oyA = fmaf(dyA * ivA, gy, ey);
    unsigned pa = (unsigned)f2bf(oxA) | ((unsigned)f2bf(oyA) << 16);
    *(unsigned*)(outbf + (size_t)nodeA * 128 + c0) = pa;
    if (hasB) {
      float oxB = fmaf(dxB * ivB, gx, ex), oyB = fmaf(dyB * ivB, gy, ey);
      unsigned pb = (unsigned)f2bf(oxB) | ((unsigned)f2bf(oyB) << 16);
      *(unsigned*)(outbf + (size_t)nodeB * 128 + c0) = pb;
    }
  }
}

// ---------------- mean pool: one wave per graph, contiguous rows -------------

__global__ __launch_bounds__(256) void pool_kernel(const unsigned short* __restrict__ hln,
                                                   const int* __restrict__ gp,
                                                   float* __restrict__ out, int G) {
  int g = (blockIdx.x * 256 + threadIdx.x) >> 6;
  int lane = threadIdx.x & 63;
  if (g >= G) return;
  int s = gp[g], e = gp[g + 1];
  float ax = 0.f, ay = 0.f;
#pragma unroll 1
  for (int i = s; i < e; ++i) {
    unsigned v = *(const unsigned*)(hln + (size_t)i * 128 + lane * 2);
    ax += bf2f((unsigned short)(v & 0xffffu));
    ay += bf2f((unsigned short)(v >> 16));
  }
  int c = e - s;
  float sc = 1.f / (float)((c > 0) ? c : 1);
  *(float2*)(out + (size_t)g * 128 + lane * 2) = make_float2(ax * sc, ay * sc);
}

// ---------------- launch ----------------

extern "C" void kernel_launch(void* const* d_in, const int* in_sizes, int n_in,
                              void* d_out, int out_size, void* d_ws, size_t ws_size,
                              hipStream_t stream) {
  const float* x = (const float*)d_in[0];
  const int* ei = (const int*)d_in[1];
  const int* batch = (const int*)d_in[2];
  const float* W1 = (const float*)d_in[3];
  const float* att_src1 = (const float*)d_in[4];
  const float* att_dst1 = (const float*)d_in[5];
  const float* b1 = (const float*)d_in[6];
  const float* W2 = (const float*)d_in[7];
  const float* att_src2 = (const float*)d_in[8];
  const float* att_dst2 = (const float*)d_in[9];
  const float* b2 = (const float*)d_in[10];
  const float* gamma = (const float*)d_in[11];
  const float* beta = (const float*)d_in[12];
  float* out = (float*)d_out;

  const int N = N_NODES_C, E = N_EDGES_C, G = NUM_GRAPHS_C;
  const int EP = E + 8;
  const int* src = ei;
  const int* dst = ei + E;

  float* p = (float*)d_ws;
  float* asrc1 = p; p += (size_t)N * 4;
  float* adst1 = p; p += (size_t)N * 4;
  float* asrc2 = p; p += N;
  float* adst2 = p; p += N;
  float* evt1 = p;  p += (size_t)EP * 4;   // [4][EP] transposed edge scores
  float* evt2 = p;  p += EP;               // [1][EP]
  int* ip = (int*)p;
  int* deg = ip;       ip += N;
  int* cursor = ip;    ip += N;
  int* col = ip;       ip += E;
  int* eslot = ip;     ip += E;
  int* bsums = ip;     ip += 256;
  int* bsums2 = ip;    ip += 256;
  int* row_ptr = ip;   ip += N + 2;
  int* graph_ptr = ip; ip += G + 2;
  unsigned short* h1bf = (unsigned short*)ip;          // [N*128] bf16; reused as LN'd rows
  unsigned short* hbbf = h1bf + (size_t)N * 128;
  unsigned short* h2bf = hbbf + (size_t)N * 128;
  unsigned short* wt1 = h2bf + (size_t)N * 128;        // [128*136] bf16 W^T padded
  unsigned short* wt2 = wt1 + 128 * 136;
  (void)ws_size; (void)in_sizes; (void)n_in; (void)out_size;

  hipMemsetAsync(deg, 0, sizeof(int) * (size_t)N, stream);
  hipMemsetAsync(cursor, 0, sizeof(int) * (size_t)N, stream);

  // CSR by destination + graph ranges + weight prep
  count_deg_kernel<<<(E + 255) / 256, 256, 0, stream>>>(dst, deg, E);
  int nblk = (N + 1023) / 1024;
  scan_kernel<<<nblk, 256, 0, stream>>>(deg, row_ptr, bsums, N);
  scan_kernel<<<1, 256, 0, stream>>>(bsums, bsums2, nullptr, nblk);
  scan_addoff_kernel<<<nblk, 256, 0, stream>>>(row_ptr, bsums2, N, E);
  fill_csr_kernel<<<(E + 255) / 256, 256, 0, stream>>>(src, dst, row_ptr, cursor, col,
                                                       eslot, E);
  graph_ptr_kernel<<<(N + 1 + 255) / 256, 256, 0, stream>>>(batch, graph_ptr, N, G);
  wprep_kernel<<<(128 * 136 + 255) / 256, 256, 0, stream>>>(W1, wt1);
  wprep_kernel<<<(128 * 136 + 255) / 256, 256, 0, stream>>>(W2, wt2);

  int pairs = (N + 1) / 2;
  int pblocks = (int)(((size_t)pairs * 64 + 255) / 256);  // 2 nodes per wave
  int eblocks = (E + 255) / 256;
  int gblocks = N / 64;  // 200000 = 64*3125 exactly

  // Layer 1: GAT(128 -> 4x32), ReLU
  gemm_att_mfma<4, false><<<gblocks, 256, 0, stream>>>(
      x, wt1, att_src1, att_dst1, h1bf, asrc1, adst1);
  edge_score_kernel<4><<<eblocks, 256, 0, stream>>>(src, dst, eslot, asrc1, adst1,
                                                    evt1, E, EP);
  gat_agg4_kernel<4, true, false><<<pblocks, 256, 0, stream>>>(
      h1bf, asrc1, adst1, evt1, EP, row_ptr, col, b1, nullptr, nullptr, hbbf, N);

  // Layer 2: GAT(128 -> 1x128) + fused LayerNorm -> bf16 rows
  gemm_att_mfma<1, true><<<gblocks, 256, 0, stream>>>(
      hbbf, wt2, att_src2, att_dst2, h2bf, asrc2, adst2);
  edge_score_kernel<1><<<eblocks, 256, 0, stream>>>(src, dst, eslot, asrc2, adst2,
                                                    evt2, E, EP);
  gat_agg4_kernel<1, false, true><<<pblocks, 256, 0, stream>>>(
      h2bf, asrc2, adst2, evt2, EP, row_ptr, col, b2, gamma, beta, h1bf, N);

  // mean pool per graph: contiguous segmented reduction -> d_out
  pool_kernel<<<(int)(((size_t)G * 64 + 255) / 256), 256, 0, stream>>>(
      h1bf, graph_ptr, out, G);
}

// Round 15
// 322.170 us; speedup vs baseline: 1.0652x; 1.0652x over previous
//
#include <hip/hip_runtime.h>
#include <cstdint>
#include <cstddef>

#define N_NODES_C 200000
#define N_EDGES_C 600000
#define NUM_GRAPHS_C 20000

constexpr float NEG_SLOPE = 0.2f;
constexpr float LN_EPS = 1e-5f;

typedef __attribute__((ext_vector_type(8))) short bf16x8;
typedef __attribute__((ext_vector_type(4))) float f32x4;

// bf16 helpers (RNE)
static __device__ __forceinline__ unsigned short f2bf(float f) {
  unsigned u = __float_as_uint(f);
  u = (u + 0x7fffu + ((u >> 16) & 1u)) >> 16;
  return (unsigned short)u;
}
static __device__ __forceinline__ float bf2f(unsigned short s) {
  return __uint_as_float(((unsigned)s) << 16);
}

// ---------------- CSR build ----------------

__global__ __launch_bounds__(256) void count_deg_kernel(const int* __restrict__ dst,
                                                        int* __restrict__ deg, int E) {
  int e = blockIdx.x * 256 + threadIdx.x;
  if (e < E) atomicAdd(&deg[dst[e]], 1);
}

// exclusive scan over n_total elements; elements with idx < npad are
// transformed deg -> ceil(deg/4)*4 + 4 (pad rows to x4 plus one all-dummy
// block). npad=0 -> plain scan.
__global__ __launch_bounds__(256) void scan_kernel(const int* __restrict__ in,
                                                   int* __restrict__ out,
                                                   int* __restrict__ bsums,
                                                   int n_total, int npad) {
  __shared__ int ss[256];
  int t = threadIdx.x;
  int base = blockIdx.x * 1024 + t * 4;
  int v[4];
  int s = 0;
#pragma unroll
  for (int j = 0; j < 4; ++j) {
    int idx = base + j;
    int x = (idx < n_total) ? in[idx] : 0;
    if (idx < npad) x = ((x + 3) & ~3) + 4;
    v[j] = x;
    s += x;
  }
  ss[t] = s;
  __syncthreads();
  for (int off = 1; off < 256; off <<= 1) {
    int x = (t >= off) ? ss[t - off] : 0;
    __syncthreads();
    ss[t] += x;
    __syncthreads();
  }
  int incl = ss[t];
  int excl = incl - s;
  if (bsums != nullptr && t == 255) bsums[blockIdx.x] = incl;
  int run = excl;
#pragma unroll
  for (int j = 0; j < 4; ++j) {
    if (base + j < n_total) out[base + j] = run;
    run += v[j];
  }
}

__global__ __launch_bounds__(256) void scan_addoff_kernel(int* __restrict__ data,
                                                          const int* __restrict__ boff,
                                                          int n_total) {
  int base = blockIdx.x * 1024 + threadIdx.x * 4;
  int add = boff[blockIdx.x];
#pragma unroll
  for (int j = 0; j < 4; ++j) {
    if (base + j < n_total) data[base + j] += add;
  }
}

__global__ __launch_bounds__(256) void fill_csr_kernel(const int* __restrict__ src,
                                                       const int* __restrict__ dst,
                                                       const int* __restrict__ row_ptr,
                                                       int* __restrict__ cursor,
                                                       int* __restrict__ col, int E) {
  int e = blockIdx.x * 256 + threadIdx.x;
  if (e < E) {
    int d = dst[e];
    int p = atomicAdd(&cursor[d], 1);
    col[row_ptr[d] + p] = src[e];
  }
}

// fill pad slots (real_deg .. row_end) with dummy node index N
__global__ __launch_bounds__(256) void pad_fill_kernel(const int* __restrict__ row_ptr,
                                                       const int* __restrict__ deg,
                                                       int* __restrict__ col, int n) {
  int i = blockIdx.x * 256 + threadIdx.x;
  if (i >= n) return;
  int s = row_ptr[i] + deg[i];
  int e = row_ptr[i + 1];
#pragma unroll 1
  for (int j = s; j < e; ++j) col[j] = n;
}

// dummy-node scores: exp(leaky(-1e30 + anything)) == 0
__global__ void dummy_init_kernel(float* __restrict__ asrc1,
                                  float* __restrict__ asrc2, int n) {
  int t = threadIdx.x;
  if (t < 4) asrc1[(size_t)n * 4 + t] = -1e30f;
  if (t == 4) asrc2[n] = -1e30f;
}

// ---------------- graph_ptr from sorted batch ----------------

__global__ __launch_bounds__(256) void graph_ptr_kernel(const int* __restrict__ batch,
                                                        int* __restrict__ gp, int n,
                                                        int G) {
  int i = blockIdx.x * 256 + threadIdx.x;
  if (i < n) {
    int prev = (i == 0) ? -1 : batch[i - 1];
    int cur = batch[i];
#pragma unroll 1
    for (int g = prev + 1; g <= cur; ++g) gp[g] = i;
  } else if (i == n) {
    int last = batch[n - 1];
#pragma unroll 1
    for (int g = last + 1; g <= G; ++g) gp[g] = n;
  }
}

// ---------------- W prep: fp32 [k][n] -> bf16 W^T padded [n][136] ----------

__global__ __launch_bounds__(256) void wprep_kernel(const float* __restrict__ W,
                                                    unsigned short* __restrict__ Wtp) {
  int idx = blockIdx.x * 256 + threadIdx.x;
  if (idx >= 128 * 136) return;
  int n = idx / 136, k = idx % 136;
  Wtp[idx] = (k < 128) ? f2bf(W[(size_t)k * 128 + n]) : (unsigned short)0;
}

// ---------------- MFMA GEMM + att-score epilogue (verified round 13) --------

template <int H, bool A_BF16>
__global__ __launch_bounds__(256) void gemm_att_mfma(
    const void* __restrict__ Av, const unsigned short* __restrict__ Wtp,
    const float* __restrict__ att_src, const float* __restrict__ att_dst,
    unsigned short* __restrict__ Cbf, float* __restrict__ asrc,
    float* __restrict__ adst) {
  __shared__ __align__(16) unsigned short Alds[64 * 136];
  __shared__ __align__(16) unsigned short Wlds[128 * 136];
  int tid = threadIdx.x;
  int lane = tid & 63;
  int wave = tid >> 6;
  int row0 = blockIdx.x * 64;

#pragma unroll
  for (int i = 0; i < 9; ++i) {
    int ch = tid + i * 256;
    if (ch < 2176) *(bf16x8*)&Wlds[ch * 8] = *(const bf16x8*)&Wtp[(size_t)ch * 8];
  }
#pragma unroll
  for (int i = 0; i < 4; ++i) {
    int ch = tid + i * 256;
    int r = ch >> 4, c = ch & 15;
    if constexpr (A_BF16) {
      bf16x8 v = *(const bf16x8*)((const unsigned short*)Av +
                                  (size_t)(row0 + r) * 128 + c * 8);
      *(bf16x8*)&Alds[r * 136 + c * 8] = v;
    } else {
      const float* A = (const float*)Av;
      float4 v0 = *(const float4*)(A + (size_t)(row0 + r) * 128 + c * 8);
      float4 v1 = *(const float4*)(A + (size_t)(row0 + r) * 128 + c * 8 + 4);
      unsigned short tmp[8] = {f2bf(v0.x), f2bf(v0.y), f2bf(v0.z), f2bf(v0.w),
                               f2bf(v1.x), f2bf(v1.y), f2bf(v1.z), f2bf(v1.w)};
      *(bf16x8*)&Alds[r * 136 + c * 8] = *(bf16x8*)tmp;
    }
  }
  __syncthreads();

  int l15 = lane & 15;
  int lg = lane >> 4;
  int wr = wave * 16;

  f32x4 acc[8];
#pragma unroll
  for (int nt = 0; nt < 8; ++nt) acc[nt] = (f32x4){0.f, 0.f, 0.f, 0.f};

#pragma unroll
  for (int ks = 0; ks < 4; ++ks) {
    bf16x8 af = *(const bf16x8*)&Alds[(wr + l15) * 136 + ks * 32 + lg * 8];
#pragma unroll
    for (int nt = 0; nt < 8; ++nt) {
      bf16x8 bfr = *(const bf16x8*)&Wlds[(nt * 16 + l15) * 136 + ks * 32 + lg * 8];
      acc[nt] = __builtin_amdgcn_mfma_f32_16x16x32_bf16(af, bfr, acc[nt], 0, 0, 0);
    }
  }

  float vsv[8], vdv[8];
#pragma unroll
  for (int nt = 0; nt < 8; ++nt) {
    vsv[nt] = att_src[nt * 16 + l15];
    vdv[nt] = att_dst[nt * 16 + l15];
  }

#pragma unroll
  for (int r = 0; r < 4; ++r) {
    int row = row0 + wr + lg * 4 + r;
#pragma unroll
    for (int nt = 0; nt < 8; ++nt) {
      Cbf[(size_t)row * 128 + nt * 16 + l15] = f2bf(acc[nt][r]);
    }
    if constexpr (H == 4) {
      float ps[4], pd[4];
#pragma unroll
      for (int hd = 0; hd < 4; ++hd) {
        ps[hd] = acc[2 * hd][r] * vsv[2 * hd] + acc[2 * hd + 1][r] * vsv[2 * hd + 1];
        pd[hd] = acc[2 * hd][r] * vdv[2 * hd] + acc[2 * hd + 1][r] * vdv[2 * hd + 1];
#pragma unroll
        for (int off = 1; off < 16; off <<= 1) {
          ps[hd] += __shfl_xor(ps[hd], off, 64);
          pd[hd] += __shfl_xor(pd[hd], off, 64);
        }
      }
      if (l15 < 4) {
        float pss = (l15 == 0) ? ps[0] : (l15 == 1) ? ps[1] : (l15 == 2) ? ps[2] : ps[3];
        float pds = (l15 == 0) ? pd[0] : (l15 == 1) ? pd[1] : (l15 == 2) ? pd[2] : pd[3];
        asrc[(size_t)row * 4 + l15] = pss;
        adst[(size_t)row * 4 + l15] = pds;
      }
    } else {
      float ps = 0.f, pd = 0.f;
#pragma unroll
      for (int nt = 0; nt < 8; ++nt) {
        ps = fmaf(acc[nt][r], vsv[nt], ps);
        pd = fmaf(acc[nt][r], vdv[nt], pd);
      }
#pragma unroll
      for (int off = 1; off < 16; off <<= 1) {
        ps += __shfl_xor(ps, off, 64);
        pd += __shfl_xor(pd, off, 64);
      }
      if (l15 == 0) {
        asrc[row] = ps;
        adst[row] = pd;
      }
    }
  }
}

// ---------------- Pass B: TWO nodes/wave, padded CSR, scalarized addressing -
// Mask-free inner loop: rows padded to x4 with a trailing all-dummy block
// (col=N, asrc[N]=-1e30 -> ee=0). Trailing clamp min(t,last) re-reads the
// dummy block for the shorter node — adds exact 0. readfirstlane puts wid /
// col values in SGPRs -> s_load for row_ptr/col, saddr-form gathers (round-13
// VALU was 84% dominated by addressing + masks, not exp: trans pipe).

template <int H, bool RELU, bool LNOUT>
__global__ __launch_bounds__(256) void gat_agg5_kernel(
    const unsigned short* __restrict__ h, const float* __restrict__ asrc,
    const float* __restrict__ adst, const int* __restrict__ row_ptr,
    const int* __restrict__ col, const float* __restrict__ bias,
    const float* __restrict__ gamma, const float* __restrict__ beta,
    unsigned short* __restrict__ outbf, int n) {
  int wid = __builtin_amdgcn_readfirstlane((blockIdx.x * 256 + threadIdx.x) >> 6);
  int lane = threadIdx.x & 63;
  int nodeA = wid * 2;       // n even -> nodeB always valid when nodeA < n
  int nodeB = nodeA + 1;
  if (nodeA >= n) return;

  int e0A = __builtin_amdgcn_readfirstlane(row_ptr[nodeA]);
  int e0B = __builtin_amdgcn_readfirstlane(row_ptr[nodeA + 1]);
  int e1B = __builtin_amdgcn_readfirstlane(row_ptr[nodeA + 2]);
  int lastA = e0B - e0A - 4;  // >= 0 (every row has >= 4 slots)
  int lastB = e1B - e0B - 4;
  int tmax = ((lastA > lastB) ? lastA : lastB) + 4;

  int c0 = lane * 2;
  const int hd = (H == 1) ? 0 : (lane >> 4);

  float adA = (H == 4) ? adst[(size_t)nodeA * 4 + hd] : adst[nodeA];
  float asA = (H == 4) ? asrc[(size_t)nodeA * 4 + hd] : asrc[nodeA];
  float adB = (H == 4) ? adst[(size_t)nodeB * 4 + hd] : adst[nodeB];
  float asB = (H == 4) ? asrc[(size_t)nodeB * 4 + hd] : asrc[nodeB];

  float xA = asA + adA; xA = (xA > 0.f) ? xA : NEG_SLOPE * xA;
  float selfeA = __expf(xA);
  float xB = asB + adB; xB = (xB > 0.f) ? xB : NEG_SLOPE * xB;
  float selfeB = __expf(xB);

  float denA = selfeA;
  float denB = selfeB;

  float2 accA, accB;
  {
    unsigned ha = *(const unsigned*)(h + (size_t)nodeA * 128 + c0);
    unsigned hb = *(const unsigned*)(h + (size_t)nodeB * 128 + c0);
    accA.x = bf2f((unsigned short)(ha & 0xffffu)) * selfeA;
    accA.y = bf2f((unsigned short)(ha >> 16)) * selfeA;
    accB.x = bf2f((unsigned short)(hb & 0xffffu)) * selfeB;
    accB.y = bf2f((unsigned short)(hb >> 16)) * selfeB;
  }

#pragma unroll 1
  for (int t = 0; t < tmax; t += 4) {
    int tA = (t < lastA) ? t : lastA;
    int tB = (t < lastB) ? t : lastB;
    int sA4[4], sB4[4];
#pragma unroll
    for (int i = 0; i < 4; ++i) {
      sA4[i] = __builtin_amdgcn_readfirstlane(col[e0A + tA + i]);
      sB4[i] = __builtin_amdgcn_readfirstlane(col[e0B + tB + i]);
    }
    float aA4[4], aB4[4];
    unsigned hA4[4], hB4[4];
#pragma unroll
    for (int i = 0; i < 4; ++i) {
      aA4[i] = (H == 4) ? asrc[(size_t)sA4[i] * 4 + hd] : asrc[sA4[i]];
      aB4[i] = (H == 4) ? asrc[(size_t)sB4[i] * 4 + hd] : asrc[sB4[i]];
      hA4[i] = *(const unsigned*)(h + (size_t)sA4[i] * 128 + c0);
      hB4[i] = *(const unsigned*)(h + (size_t)sB4[i] * 128 + c0);
    }
#pragma unroll
    for (int i = 0; i < 4; ++i) {
      float ya = aA4[i] + adA; ya = (ya > 0.f) ? ya : NEG_SLOPE * ya;
      float eeA = __expf(ya);
      float yb = aB4[i] + adB; yb = (yb > 0.f) ? yb : NEG_SLOPE * yb;
      float eeB = __expf(yb);
      denA += eeA;
      denB += eeB;
      accA.x = fmaf(bf2f((unsigned short)(hA4[i] & 0xffffu)), eeA, accA.x);
      accA.y = fmaf(bf2f((unsigned short)(hA4[i] >> 16)), eeA, accA.y);
      accB.x = fmaf(bf2f((unsigned short)(hB4[i] & 0xffffu)), eeB, accB.x);
      accB.y = fmaf(bf2f((unsigned short)(hB4[i] >> 16)), eeB, accB.y);
    }
  }

  float invA = 1.f / denA;
  float invB = 1.f / denB;

  float bx = bias[c0], by = bias[c0 + 1];
  accA.x = fmaf(accA.x, invA, bx);
  accA.y = fmaf(accA.y, invA, by);
  accB.x = fmaf(accB.x, invB, bx);
  accB.y = fmaf(accB.y, invB, by);
  if (RELU) {
    accA.x = fmaxf(accA.x, 0.f); accA.y = fmaxf(accA.y, 0.f);
    accB.x = fmaxf(accB.x, 0.f); accB.y = fmaxf(accB.y, 0.f);
  }

  if (!LNOUT) {
    unsigned pa = (unsigned)f2bf(accA.x) | ((unsigned)f2bf(accA.y) << 16);
    unsigned pb = (unsigned)f2bf(accB.x) | ((unsigned)f2bf(accB.y) << 16);
    *(unsigned*)(outbf + (size_t)nodeA * 128 + c0) = pa;
    *(unsigned*)(outbf + (size_t)nodeB * 128 + c0) = pb;
  } else {
    float sA = accA.x + accA.y;
    float sB = accB.x + accB.y;
#pragma unroll
    for (int off = 1; off < 64; off <<= 1) {
      sA += __shfl_xor(sA, off, 64);
      sB += __shfl_xor(sB, off, 64);
    }
    float muA = sA * (1.f / 128.f), muB = sB * (1.f / 128.f);
    float dxA = accA.x - muA, dyA = accA.y - muA;
    float dxB = accB.x - muB, dyB = accB.y - muB;
    float vA = dxA * dxA + dyA * dyA;
    float vB = dxB * dxB + dyB * dyB;
#pragma unroll
    for (int off = 1; off < 64; off <<= 1) {
      vA += __shfl_xor(vA, off, 64);
      vB += __shfl_xor(vB, off, 64);
    }
    float ivA = rsqrtf(vA * (1.f / 128.f) + LN_EPS);
    float ivB = rsqrtf(vB * (1.f / 128.f) + LN_EPS);
    float gx = gamma[c0], gy = gamma[c0 + 1];
    float ex = beta[c0], ey = beta[c0 + 1];
    float oxA = fmaf(dxA * ivA, gx, ex), oyA = fmaf(dyA * ivA, gy, ey);
    float oxB = fmaf(dxB * ivB, gx, ex), oyB = fmaf(dyB * ivB, gy, ey);
    unsigned pa = (unsigned)f2bf(oxA) | ((unsigned)f2bf(oyA) << 16);
    unsigned pb = (unsigned)f2bf(oxB) | ((unsigned)f2bf(oyB) << 16);
    *(unsigned*)(outbf + (size_t)nodeA * 128 + c0) = pa;
    *(unsigned*)(outbf + (size_t)nodeB * 128 + c0) = pb;
  }
}

// ---------------- mean pool: one wave per graph, contiguous rows -------------

__global__ __launch_bounds__(256) void pool_kernel(const unsigned short* __restrict__ hln,
                                                   const int* __restrict__ gp,
                                                   float* __restrict__ out, int G) {
  int g = (blockIdx.x * 256 + threadIdx.x) >> 6;
  int lane = threadIdx.x & 63;
  if (g >= G) return;
  int s = gp[g], e = gp[g + 1];
  float ax = 0.f, ay = 0.f;
#pragma unroll 1
  for (int i = s; i < e; ++i) {
    unsigned v = *(const unsigned*)(hln + (size_t)i * 128 + lane * 2);
    ax += bf2f((unsigned short)(v & 0xffffu));
    ay += bf2f((unsigned short)(v >> 16));
  }
  int c = e - s;
  float sc = 1.f / (float)((c > 0) ? c : 1);
  *(float2*)(out + (size_t)g * 128 + lane * 2) = make_float2(ax * sc, ay * sc);
}

// ---------------- launch ----------------

extern "C" void kernel_launch(void* const* d_in, const int* in_sizes, int n_in,
                              void* d_out, int out_size, void* d_ws, size_t ws_size,
                              hipStream_t stream) {
  const float* x = (const float*)d_in[0];
  const int* ei = (const int*)d_in[1];
  const int* batch = (const int*)d_in[2];
  const float* W1 = (const float*)d_in[3];
  const float* att_src1 = (const float*)d_in[4];
  const float* att_dst1 = (const float*)d_in[5];
  const float* b1 = (const float*)d_in[6];
  const float* W2 = (const float*)d_in[7];
  const float* att_src2 = (const float*)d_in[8];
  const float* att_dst2 = (const float*)d_in[9];
  const float* b2 = (const float*)d_in[10];
  const float* gamma = (const float*)d_in[11];
  const float* beta = (const float*)d_in[12];
  float* out = (float*)d_out;

  const int N = N_NODES_C, E = N_EDGES_C, G = NUM_GRAPHS_C;
  const int COLSZ = E + 7 * N;  // padded CSR upper bound
  const int* src = ei;
  const int* dst = ei + E;

  float* p = (float*)d_ws;
  float* asrc1 = p; p += (size_t)(N + 1) * 4;  // +dummy row (asrc[N]=-1e30)
  float* adst1 = p; p += (size_t)N * 4;
  float* asrc2 = p; p += N + 1;
  float* adst2 = p; p += N;
  int* ip = (int*)p;
  int* deg = ip;       ip += N + 1;  // deg[N]=0 (scanned as element N)
  int* cursor = ip;    ip += N;
  int* col = ip;       ip += COLSZ;
  int* bsums = ip;     ip += 256;
  int* bsums2 = ip;    ip += 256;
  int* row_ptr = ip;   ip += N + 2;
  int* graph_ptr = ip; ip += G + 2;
  unsigned short* h1bf = (unsigned short*)ip;          // [(N+1)*128] bf16 (+dummy row)
  unsigned short* hbbf = h1bf + (size_t)(N + 1) * 128;
  unsigned short* h2bf = hbbf + (size_t)(N + 1) * 128;
  unsigned short* wt1 = h2bf + (size_t)(N + 1) * 128;  // [128*136] bf16 W^T padded
  unsigned short* wt2 = wt1 + 128 * 136;
  (void)ws_size; (void)in_sizes; (void)n_in; (void)out_size;

  hipMemsetAsync(deg, 0, sizeof(int) * (size_t)(N + 1), stream);
  hipMemsetAsync(cursor, 0, sizeof(int) * (size_t)N, stream);

  // CSR (padded rows) + graph ranges + weight prep + dummy scores
  count_deg_kernel<<<(E + 255) / 256, 256, 0, stream>>>(dst, deg, E);
  int nblk = (N + 1 + 1023) / 1024;
  scan_kernel<<<nblk, 256, 0, stream>>>(deg, row_ptr, bsums, N + 1, N);
  scan_kernel<<<1, 256, 0, stream>>>(bsums, bsums2, nullptr, nblk, 0);
  scan_addoff_kernel<<<nblk, 256, 0, stream>>>(row_ptr, bsums2, N + 1);
  fill_csr_kernel<<<(E + 255) / 256, 256, 0, stream>>>(src, dst, row_ptr, cursor, col, E);
  pad_fill_kernel<<<(N + 255) / 256, 256, 0, stream>>>(row_ptr, deg, col, N);
  graph_ptr_kernel<<<(N + 1 + 255) / 256, 256, 0, stream>>>(batch, graph_ptr, N, G);
  wprep_kernel<<<(128 * 136 + 255) / 256, 256, 0, stream>>>(W1, wt1);
  wprep_kernel<<<(128 * 136 + 255) / 256, 256, 0, stream>>>(W2, wt2);
  dummy_init_kernel<<<1, 64, 0, stream>>>(asrc1, asrc2, N);

  int pairs = N / 2;  // N even
  int pblocks = (int)(((size_t)pairs * 64 + 255) / 256);  // 2 nodes per wave
  int gblocks = N / 64;  // 200000 = 64*3125 exactly

  // Layer 1: GAT(128 -> 4x32), ReLU
  gemm_att_mfma<4, false><<<gblocks, 256, 0, stream>>>(
      x, wt1, att_src1, att_dst1, h1bf, asrc1, adst1);
  gat_agg5_kernel<4, true, false><<<pblocks, 256, 0, stream>>>(
      h1bf, asrc1, adst1, row_ptr, col, b1, nullptr, nullptr, hbbf, N);

  // Layer 2: GAT(128 -> 1x128) + fused LayerNorm -> bf16 rows
  gemm_att_mfma<1, true><<<gblocks, 256, 0, stream>>>(
      hbbf, wt2, att_src2, att_dst2, h2bf, asrc2, adst2);
  gat_agg5_kernel<1, false, true><<<pblocks, 256, 0, stream>>>(
      h2bf, asrc2, adst2, row_ptr, col, b2, gamma, beta, h1bf, N);

  // mean pool per graph: contiguous segmented reduction -> d_out
  pool_kernel<<<(int)(((size_t)G * 64 + 255) / 256), 256, 0, stream>>>(
      h1bf, graph_ptr, out, G);
}

// Round 16
// 298.661 us; speedup vs baseline: 1.1490x; 1.0787x over previous
//
#include <hip/hip_runtime.h>
#include <cstdint>
#include <cstddef>

#define N_NODES_C 200000
#define N_EDGES_C 600000
#define NUM_GRAPHS_C 20000

constexpr float NEG_SLOPE = 0.2f;
constexpr float LN_EPS = 1e-5f;

typedef __attribute__((ext_vector_type(8))) short bf16x8;
typedef __attribute__((ext_vector_type(4))) float f32x4;

// bf16 helpers (RNE)
static __device__ __forceinline__ unsigned short f2bf(float f) {
  unsigned u = __float_as_uint(f);
  u = (u + 0x7fffu + ((u >> 16) & 1u)) >> 16;
  return (unsigned short)u;
}
static __device__ __forceinline__ float bf2f(unsigned short s) {
  return __uint_as_float(((unsigned)s) << 16);
}
// unpack packed pair of bf16 from a dword (1 VALU each)
static __device__ __forceinline__ float bfu_lo(unsigned u) {
  return __uint_as_float(u << 16);
}
static __device__ __forceinline__ float bfu_hi(unsigned u) {
  return __uint_as_float(u & 0xffff0000u);
}

// ---------------- CSR build ----------------

__global__ __launch_bounds__(256) void count_deg_kernel(const int* __restrict__ dst,
                                                        int* __restrict__ deg, int E) {
  int e = blockIdx.x * 256 + threadIdx.x;
  if (e < E) atomicAdd(&deg[dst[e]], 1);
}

// exclusive scan over n_total elements; elements with idx < npad are
// transformed deg -> ceil(deg/4)*4 (pad rows to x4 — NO extra block: round-15
// regression was the always-on dummy block doubling typical trip counts).
__global__ __launch_bounds__(256) void scan_kernel(const int* __restrict__ in,
                                                   int* __restrict__ out,
                                                   int* __restrict__ bsums,
                                                   int n_total, int npad) {
  __shared__ int ss[256];
  int t = threadIdx.x;
  int base = blockIdx.x * 1024 + t * 4;
  int v[4];
  int s = 0;
#pragma unroll
  for (int j = 0; j < 4; ++j) {
    int idx = base + j;
    int x = (idx < n_total) ? in[idx] : 0;
    if (idx < npad) x = (x + 3) & ~3;
    v[j] = x;
    s += x;
  }
  ss[t] = s;
  __syncthreads();
  for (int off = 1; off < 256; off <<= 1) {
    int x = (t >= off) ? ss[t - off] : 0;
    __syncthreads();
    ss[t] += x;
    __syncthreads();
  }
  int incl = ss[t];
  int excl = incl - s;
  if (bsums != nullptr && t == 255) bsums[blockIdx.x] = incl;
  int run = excl;
#pragma unroll
  for (int j = 0; j < 4; ++j) {
    if (base + j < n_total) out[base + j] = run;
    run += v[j];
  }
}

__global__ __launch_bounds__(256) void scan_addoff_kernel(int* __restrict__ data,
                                                          const int* __restrict__ boff,
                                                          int n_total) {
  int base = blockIdx.x * 1024 + threadIdx.x * 4;
  int add = boff[blockIdx.x];
#pragma unroll
  for (int j = 0; j < 4; ++j) {
    if (base + j < n_total) data[base + j] += add;
  }
}

__global__ __launch_bounds__(256) void fill_csr_kernel(const int* __restrict__ src,
                                                       const int* __restrict__ dst,
                                                       const int* __restrict__ row_ptr,
                                                       int* __restrict__ cursor,
                                                       int* __restrict__ col, int E) {
  int e = blockIdx.x * 256 + threadIdx.x;
  if (e < E) {
    int d = dst[e];
    int p = atomicAdd(&cursor[d], 1);
    col[row_ptr[d] + p] = src[e];
  }
}

// fill pad slots (real_deg .. row_end) with dummy node index N
__global__ __launch_bounds__(256) void pad_fill_kernel(const int* __restrict__ row_ptr,
                                                       const int* __restrict__ deg,
                                                       int* __restrict__ col, int n) {
  int i = blockIdx.x * 256 + threadIdx.x;
  if (i >= n) return;
  int s = row_ptr[i] + deg[i];
  int e = row_ptr[i + 1];
#pragma unroll 1
  for (int j = s; j < e; ++j) col[j] = n;
}

// dummy-node scores: exp(leaky(-1e30 + anything)) == 0
__global__ void dummy_init_kernel(float* __restrict__ asrc1,
                                  float* __restrict__ asrc2, int n) {
  int t = threadIdx.x;
  if (t < 4) asrc1[(size_t)n * 4 + t] = -1e30f;
  if (t == 4) asrc2[n] = -1e30f;
}

// ---------------- graph_ptr from sorted batch ----------------

__global__ __launch_bounds__(256) void graph_ptr_kernel(const int* __restrict__ batch,
                                                        int* __restrict__ gp, int n,
                                                        int G) {
  int i = blockIdx.x * 256 + threadIdx.x;
  if (i < n) {
    int prev = (i == 0) ? -1 : batch[i - 1];
    int cur = batch[i];
#pragma unroll 1
    for (int g = prev + 1; g <= cur; ++g) gp[g] = i;
  } else if (i == n) {
    int last = batch[n - 1];
#pragma unroll 1
    for (int g = last + 1; g <= G; ++g) gp[g] = n;
  }
}

// ---------------- W prep: fp32 [k][n] -> bf16 W^T padded [n][136] ----------

__global__ __launch_bounds__(256) void wprep_kernel(const float* __restrict__ W,
                                                    unsigned short* __restrict__ Wtp) {
  int idx = blockIdx.x * 256 + threadIdx.x;
  if (idx >= 128 * 136) return;
  int n = idx / 136, k = idx % 136;
  Wtp[idx] = (k < 128) ? f2bf(W[(size_t)k * 128 + n]) : (unsigned short)0;
}

// ---------------- MFMA GEMM + att-score epilogue (verified round 13) --------

template <int H, bool A_BF16>
__global__ __launch_bounds__(256) void gemm_att_mfma(
    const void* __restrict__ Av, const unsigned short* __restrict__ Wtp,
    const float* __restrict__ att_src, const float* __restrict__ att_dst,
    unsigned short* __restrict__ Cbf, float* __restrict__ asrc,
    float* __restrict__ adst) {
  __shared__ __align__(16) unsigned short Alds[64 * 136];
  __shared__ __align__(16) unsigned short Wlds[128 * 136];
  int tid = threadIdx.x;
  int lane = tid & 63;
  int wave = tid >> 6;
  int row0 = blockIdx.x * 64;

#pragma unroll
  for (int i = 0; i < 9; ++i) {
    int ch = tid + i * 256;
    if (ch < 2176) *(bf16x8*)&Wlds[ch * 8] = *(const bf16x8*)&Wtp[(size_t)ch * 8];
  }
#pragma unroll
  for (int i = 0; i < 4; ++i) {
    int ch = tid + i * 256;
    int r = ch >> 4, c = ch & 15;
    if constexpr (A_BF16) {
      bf16x8 v = *(const bf16x8*)((const unsigned short*)Av +
                                  (size_t)(row0 + r) * 128 + c * 8);
      *(bf16x8*)&Alds[r * 136 + c * 8] = v;
    } else {
      const float* A = (const float*)Av;
      float4 v0 = *(const float4*)(A + (size_t)(row0 + r) * 128 + c * 8);
      float4 v1 = *(const float4*)(A + (size_t)(row0 + r) * 128 + c * 8 + 4);
      unsigned short tmp[8] = {f2bf(v0.x), f2bf(v0.y), f2bf(v0.z), f2bf(v0.w),
                               f2bf(v1.x), f2bf(v1.y), f2bf(v1.z), f2bf(v1.w)};
      *(bf16x8*)&Alds[r * 136 + c * 8] = *(bf16x8*)tmp;
    }
  }
  __syncthreads();

  int l15 = lane & 15;
  int lg = lane >> 4;
  int wr = wave * 16;

  f32x4 acc[8];
#pragma unroll
  for (int nt = 0; nt < 8; ++nt) acc[nt] = (f32x4){0.f, 0.f, 0.f, 0.f};

#pragma unroll
  for (int ks = 0; ks < 4; ++ks) {
    bf16x8 af = *(const bf16x8*)&Alds[(wr + l15) * 136 + ks * 32 + lg * 8];
#pragma unroll
    for (int nt = 0; nt < 8; ++nt) {
      bf16x8 bfr = *(const bf16x8*)&Wlds[(nt * 16 + l15) * 136 + ks * 32 + lg * 8];
      acc[nt] = __builtin_amdgcn_mfma_f32_16x16x32_bf16(af, bfr, acc[nt], 0, 0, 0);
    }
  }

  float vsv[8], vdv[8];
#pragma unroll
  for (int nt = 0; nt < 8; ++nt) {
    vsv[nt] = att_src[nt * 16 + l15];
    vdv[nt] = att_dst[nt * 16 + l15];
  }

#pragma unroll
  for (int r = 0; r < 4; ++r) {
    int row = row0 + wr + lg * 4 + r;
#pragma unroll
    for (int nt = 0; nt < 8; ++nt) {
      Cbf[(size_t)row * 128 + nt * 16 + l15] = f2bf(acc[nt][r]);
    }
    if constexpr (H == 4) {
      float ps[4], pd[4];
#pragma unroll
      for (int hd = 0; hd < 4; ++hd) {
        ps[hd] = acc[2 * hd][r] * vsv[2 * hd] + acc[2 * hd + 1][r] * vsv[2 * hd + 1];
        pd[hd] = acc[2 * hd][r] * vdv[2 * hd] + acc[2 * hd + 1][r] * vdv[2 * hd + 1];
#pragma unroll
        for (int off = 1; off < 16; off <<= 1) {
          ps[hd] += __shfl_xor(ps[hd], off, 64);
          pd[hd] += __shfl_xor(pd[hd], off, 64);
        }
      }
      if (l15 < 4) {
        float pss = (l15 == 0) ? ps[0] : (l15 == 1) ? ps[1] : (l15 == 2) ? ps[2] : ps[3];
        float pds = (l15 == 0) ? pd[0] : (l15 == 1) ? pd[1] : (l15 == 2) ? pd[2] : pd[3];
        asrc[(size_t)row * 4 + l15] = pss;
        adst[(size_t)row * 4 + l15] = pds;
      }
    } else {
      float ps = 0.f, pd = 0.f;
#pragma unroll
      for (int nt = 0; nt < 8; ++nt) {
        ps = fmaf(acc[nt][r], vsv[nt], ps);
        pd = fmaf(acc[nt][r], vdv[nt], pd);
      }
#pragma unroll
      for (int off = 1; off < 16; off <<= 1) {
        ps += __shfl_xor(ps, off, 64);
        pd += __shfl_xor(pd, off, 64);
      }
      if (l15 == 0) {
        asrc[row] = ps;
        adst[row] = pd;
      }
    }
  }
}

// ---------------- Pass B: half-wave per node (32 lanes x 4 channels) --------
// 2 nodes per wave, lanes 0-31 node A / lanes 32-63 node B: one VALU
// instruction serves both nodes -> gather/exp/addressing instruction count
// halves vs round-13 (which was 84% VALUBusy). Rows padded to x4 (dummy node
// N, asrc[N]=-1e30 -> ee=0 exactly) -> mask-free 4-wide body; col loads are
// one int4 (16B, aligned since padded row starts are x4). Per-half loop
// divergence (t < len) is handled by exec mask — no clamps, no cndmasks,
// no readfirstlane (round-15 lessons).

template <int H, bool RELU, bool LNOUT>
__global__ __launch_bounds__(256) void gat_agg6_kernel(
    const unsigned short* __restrict__ h, const float* __restrict__ asrc,
    const float* __restrict__ adst, const int* __restrict__ row_ptr,
    const int* __restrict__ col, const float* __restrict__ bias,
    const float* __restrict__ gamma, const float* __restrict__ beta,
    unsigned short* __restrict__ outbf, int n) {
  int wid = (blockIdx.x * 256 + threadIdx.x) >> 6;
  int lane = threadIdx.x & 63;
  int half = lane >> 5;
  int cl = lane & 31;
  int node = wid * 2 + half;  // n even -> wave-uniform validity
  if (node >= n) return;

  int e0 = row_ptr[node];
  int len = row_ptr[node + 1] - e0;  // padded to x4
  int c0 = cl * 4;
  const int hd = (H == 1) ? 0 : (cl >> 3);  // 32 channels per head

  float ad = (H == 4) ? adst[(size_t)node * 4 + hd] : adst[node];
  float as_ = (H == 4) ? asrc[(size_t)node * 4 + hd] : asrc[node];
  float x = as_ + ad;
  x = (x > 0.f) ? x : NEG_SLOPE * x;
  float selfe = __expf(x);
  float den = selfe;

  float a0, a1, a2, a3;
  {
    uint2 hs = *(const uint2*)(h + (size_t)node * 128 + c0);
    a0 = bfu_lo(hs.x) * selfe;
    a1 = bfu_hi(hs.x) * selfe;
    a2 = bfu_lo(hs.y) * selfe;
    a3 = bfu_hi(hs.y) * selfe;
  }

#pragma unroll 1
  for (int t = 0; t < len; t += 4) {
    int4 s4 = *(const int4*)(col + e0 + t);  // 16B aligned
    float sc0, sc1, sc2, sc3;
    if constexpr (H == 4) {
      sc0 = asrc[(size_t)s4.x * 4 + hd];
      sc1 = asrc[(size_t)s4.y * 4 + hd];
      sc2 = asrc[(size_t)s4.z * 4 + hd];
      sc3 = asrc[(size_t)s4.w * 4 + hd];
    } else {
      sc0 = asrc[s4.x];
      sc1 = asrc[s4.y];
      sc2 = asrc[s4.z];
      sc3 = asrc[s4.w];
    }
    uint2 h0 = *(const uint2*)(h + (size_t)s4.x * 128 + c0);
    uint2 h1 = *(const uint2*)(h + (size_t)s4.y * 128 + c0);
    uint2 h2 = *(const uint2*)(h + (size_t)s4.z * 128 + c0);
    uint2 h3 = *(const uint2*)(h + (size_t)s4.w * 128 + c0);

    float y0 = sc0 + ad; y0 = (y0 > 0.f) ? y0 : NEG_SLOPE * y0;
    float e0f = __expf(y0);
    float y1 = sc1 + ad; y1 = (y1 > 0.f) ? y1 : NEG_SLOPE * y1;
    float e1f = __expf(y1);
    float y2 = sc2 + ad; y2 = (y2 > 0.f) ? y2 : NEG_SLOPE * y2;
    float e2f = __expf(y2);
    float y3 = sc3 + ad; y3 = (y3 > 0.f) ? y3 : NEG_SLOPE * y3;
    float e3f = __expf(y3);
    den += e0f + e1f + e2f + e3f;

    a0 = fmaf(bfu_lo(h0.x), e0f, a0);
    a1 = fmaf(bfu_hi(h0.x), e0f, a1);
    a2 = fmaf(bfu_lo(h0.y), e0f, a2);
    a3 = fmaf(bfu_hi(h0.y), e0f, a3);
    a0 = fmaf(bfu_lo(h1.x), e1f, a0);
    a1 = fmaf(bfu_hi(h1.x), e1f, a1);
    a2 = fmaf(bfu_lo(h1.y), e1f, a2);
    a3 = fmaf(bfu_hi(h1.y), e1f, a3);
    a0 = fmaf(bfu_lo(h2.x), e2f, a0);
    a1 = fmaf(bfu_hi(h2.x), e2f, a1);
    a2 = fmaf(bfu_lo(h2.y), e2f, a2);
    a3 = fmaf(bfu_hi(h2.y), e2f, a3);
    a0 = fmaf(bfu_lo(h3.x), e3f, a0);
    a1 = fmaf(bfu_hi(h3.x), e3f, a1);
    a2 = fmaf(bfu_lo(h3.y), e3f, a2);
    a3 = fmaf(bfu_hi(h3.y), e3f, a3);
  }

  float inv = 1.f / den;
  float4 b4 = *(const float4*)(bias + c0);
  float o0 = fmaf(a0, inv, b4.x);
  float o1 = fmaf(a1, inv, b4.y);
  float o2 = fmaf(a2, inv, b4.z);
  float o3 = fmaf(a3, inv, b4.w);
  if (RELU) {
    o0 = fmaxf(o0, 0.f);
    o1 = fmaxf(o1, 0.f);
    o2 = fmaxf(o2, 0.f);
    o3 = fmaxf(o3, 0.f);
  }

  if (!LNOUT) {
    uint2 pv;
    pv.x = (unsigned)f2bf(o0) | ((unsigned)f2bf(o1) << 16);
    pv.y = (unsigned)f2bf(o2) | ((unsigned)f2bf(o3) << 16);
    *(uint2*)(outbf + (size_t)node * 128 + c0) = pv;
  } else {
    // LayerNorm over 128 channels held by the 32-lane half (4/lane);
    // shfl_xor offsets 1..16 stay within the half (bit5 preserved).
    float ssum = o0 + o1 + o2 + o3;
#pragma unroll
    for (int off = 1; off < 32; off <<= 1) ssum += __shfl_xor(ssum, off, 64);
    float mu = ssum * (1.f / 128.f);
    float d0 = o0 - mu, d1 = o1 - mu, d2 = o2 - mu, d3 = o3 - mu;
    float vs2 = d0 * d0 + d1 * d1 + d2 * d2 + d3 * d3;
#pragma unroll
    for (int off = 1; off < 32; off <<= 1) vs2 += __shfl_xor(vs2, off, 64);
    float ivn = rsqrtf(vs2 * (1.f / 128.f) + LN_EPS);
    float4 g4 = *(const float4*)(gamma + c0);
    float4 be4 = *(const float4*)(beta + c0);
    float q0 = fmaf(d0 * ivn, g4.x, be4.x);
    float q1 = fmaf(d1 * ivn, g4.y, be4.y);
    float q2 = fmaf(d2 * ivn, g4.z, be4.z);
    float q3 = fmaf(d3 * ivn, g4.w, be4.w);
    uint2 pv;
    pv.x = (unsigned)f2bf(q0) | ((unsigned)f2bf(q1) << 16);
    pv.y = (unsigned)f2bf(q2) | ((unsigned)f2bf(q3) << 16);
    *(uint2*)(outbf + (size_t)node * 128 + c0) = pv;
  }
}

// ---------------- mean pool: one wave per graph, contiguous rows -------------

__global__ __launch_bounds__(256) void pool_kernel(const unsigned short* __restrict__ hln,
                                                   const int* __restrict__ gp,
                                                   float* __restrict__ out, int G) {
  int g = (blockIdx.x * 256 + threadIdx.x) >> 6;
  int lane = threadIdx.x & 63;
  if (g >= G) return;
  int s = gp[g], e = gp[g + 1];
  float ax = 0.f, ay = 0.f;
#pragma unroll 1
  for (int i = s; i < e; ++i) {
    unsigned v = *(const unsigned*)(hln + (size_t)i * 128 + lane * 2);
    ax += bfu_lo(v);
    ay += bfu_hi(v);
  }
  int c = e - s;
  float sc = 1.f / (float)((c > 0) ? c : 1);
  *(float2*)(out + (size_t)g * 128 + lane * 2) = make_float2(ax * sc, ay * sc);
}

// ---------------- launch ----------------

extern "C" void kernel_launch(void* const* d_in, const int* in_sizes, int n_in,
                              void* d_out, int out_size, void* d_ws, size_t ws_size,
                              hipStream_t stream) {
  const float* x = (const float*)d_in[0];
  const int* ei = (const int*)d_in[1];
  const int* batch = (const int*)d_in[2];
  const float* W1 = (const float*)d_in[3];
  const float* att_src1 = (const float*)d_in[4];
  const float* att_dst1 = (const float*)d_in[5];
  const float* b1 = (const float*)d_in[6];
  const float* W2 = (const float*)d_in[7];
  const float* att_src2 = (const float*)d_in[8];
  const float* att_dst2 = (const float*)d_in[9];
  const float* b2 = (const float*)d_in[10];
  const float* gamma = (const float*)d_in[11];
  const float* beta = (const float*)d_in[12];
  float* out = (float*)d_out;

  const int N = N_NODES_C, E = N_EDGES_C, G = NUM_GRAPHS_C;
  const int COLSZ = E + 3 * N + 16;  // padded CSR upper bound (pad <= 3/row)
  const int* src = ei;
  const int* dst = ei + E;

  float* p = (float*)d_ws;
  float* asrc1 = p; p += (size_t)(N + 1) * 4;  // +dummy row (asrc[N]=-1e30)
  float* adst1 = p; p += (size_t)N * 4;
  float* asrc2 = p; p += N + 1;
  float* adst2 = p; p += N;
  int* ip = (int*)p;
  int* deg = ip;       ip += N + 1;  // deg[N]=0 (scanned as element N)
  int* cursor = ip;    ip += N;
  int* col = ip;       ip += COLSZ;
  int* bsums = ip;     ip += 256;
  int* bsums2 = ip;    ip += 256;
  int* row_ptr = ip;   ip += N + 2;
  int* graph_ptr = ip; ip += G + 2;
  unsigned short* h1bf = (unsigned short*)ip;          // [(N+1)*128] bf16 (+dummy row)
  unsigned short* hbbf = h1bf + (size_t)(N + 1) * 128;
  unsigned short* h2bf = hbbf + (size_t)(N + 1) * 128;
  unsigned short* wt1 = h2bf + (size_t)(N + 1) * 128;  // [128*136] bf16 W^T padded
  unsigned short* wt2 = wt1 + 128 * 136;
  (void)ws_size; (void)in_sizes; (void)n_in; (void)out_size;

  hipMemsetAsync(deg, 0, sizeof(int) * (size_t)(N + 1), stream);
  hipMemsetAsync(cursor, 0, sizeof(int) * (size_t)N, stream);

  // CSR (rows padded to x4) + graph ranges + weight prep + dummy scores
  count_deg_kernel<<<(E + 255) / 256, 256, 0, stream>>>(dst, deg, E);
  int nblk = (N + 1 + 1023) / 1024;
  scan_kernel<<<nblk, 256, 0, stream>>>(deg, row_ptr, bsums, N + 1, N);
  scan_kernel<<<1, 256, 0, stream>>>(bsums, bsums2, nullptr, nblk, 0);
  scan_addoff_kernel<<<nblk, 256, 0, stream>>>(row_ptr, bsums2, N + 1);
  fill_csr_kernel<<<(E + 255) / 256, 256, 0, stream>>>(src, dst, row_ptr, cursor, col, E);
  pad_fill_kernel<<<(N + 255) / 256, 256, 0, stream>>>(row_ptr, deg, col, N);
  graph_ptr_kernel<<<(N + 1 + 255) / 256, 256, 0, stream>>>(batch, graph_ptr, N, G);
  wprep_kernel<<<(128 * 136 + 255) / 256, 256, 0, stream>>>(W1, wt1);
  wprep_kernel<<<(128 * 136 + 255) / 256, 256, 0, stream>>>(W2, wt2);
  dummy_init_kernel<<<1, 64, 0, stream>>>(asrc1, asrc2, N);

  int pblocks = N / 8;   // 2 nodes/wave, 4 waves/block; N even, 200000/8 exact
  int gblocks = N / 64;  // 200000 = 64*3125 exactly

  // Layer 1: GAT(128 -> 4x32), ReLU
  gemm_att_mfma<4, false><<<gblocks, 256, 0, stream>>>(
      x, wt1, att_src1, att_dst1, h1bf, asrc1, adst1);
  gat_agg6_kernel<4, true, false><<<pblocks, 256, 0, stream>>>(
      h1bf, asrc1, adst1, row_ptr, col, b1, nullptr, nullptr, hbbf, N);

  // Layer 2: GAT(128 -> 1x128) + fused LayerNorm -> bf16 rows
  gemm_att_mfma<1, true><<<gblocks, 256, 0, stream>>>(
      hbbf, wt2, att_src2, att_dst2, h2bf, asrc2, adst2);
  gat_agg6_kernel<1, false, true><<<pblocks, 256, 0, stream>>>(
      h2bf, asrc2, adst2, row_ptr, col, b2, gamma, beta, h1bf, N);

  // mean pool per graph: contiguous segmented reduction -> d_out
  pool_kernel<<<(int)(((size_t)G * 64 + 255) / 256), 256, 0, stream>>>(
      h1bf, graph_ptr, out, G);
}

// Round 17
// 293.308 us; speedup vs baseline: 1.1700x; 1.0183x over previous
//
#include <hip/hip_runtime.h>
#include <cstdint>
#include <cstddef>

#define N_NODES_C 200000
#define N_EDGES_C 600000
#define NUM_GRAPHS_C 20000

constexpr float NEG_SLOPE = 0.2f;
constexpr float LN_EPS = 1e-5f;

typedef __attribute__((ext_vector_type(8))) short bf16x8;
typedef __attribute__((ext_vector_type(4))) float f32x4;

// bf16 helpers (RNE)
static __device__ __forceinline__ unsigned short f2bf(float f) {
  unsigned u = __float_as_uint(f);
  u = (u + 0x7fffu + ((u >> 16) & 1u)) >> 16;
  return (unsigned short)u;
}
static __device__ __forceinline__ float bf2f(unsigned short s) {
  return __uint_as_float(((unsigned)s) << 16);
}
// unpack packed pair of bf16 from a dword (1 VALU each)
static __device__ __forceinline__ float bfu_lo(unsigned u) {
  return __uint_as_float(u << 16);
}
static __device__ __forceinline__ float bfu_hi(unsigned u) {
  return __uint_as_float(u & 0xffff0000u);
}

// ---------------- CSR build ----------------

__global__ __launch_bounds__(256) void count_deg_kernel(const int* __restrict__ dst,
                                                        int* __restrict__ deg, int E) {
  int e = blockIdx.x * 256 + threadIdx.x;
  if (e < E) atomicAdd(&deg[dst[e]], 1);
}

// exclusive scan over n_total elements; elements with idx < npad are
// transformed deg -> ceil(deg/4)*4 (pad rows to x4; no extra dummy block).
__global__ __launch_bounds__(256) void scan_kernel(const int* __restrict__ in,
                                                   int* __restrict__ out,
                                                   int* __restrict__ bsums,
                                                   int n_total, int npad) {
  __shared__ int ss[256];
  int t = threadIdx.x;
  int base = blockIdx.x * 1024 + t * 4;
  int v[4];
  int s = 0;
#pragma unroll
  for (int j = 0; j < 4; ++j) {
    int idx = base + j;
    int x = (idx < n_total) ? in[idx] : 0;
    if (idx < npad) x = (x + 3) & ~3;
    v[j] = x;
    s += x;
  }
  ss[t] = s;
  __syncthreads();
  for (int off = 1; off < 256; off <<= 1) {
    int x = (t >= off) ? ss[t - off] : 0;
    __syncthreads();
    ss[t] += x;
    __syncthreads();
  }
  int incl = ss[t];
  int excl = incl - s;
  if (bsums != nullptr && t == 255) bsums[blockIdx.x] = incl;
  int run = excl;
#pragma unroll
  for (int j = 0; j < 4; ++j) {
    if (base + j < n_total) out[base + j] = run;
    run += v[j];
  }
}

__global__ __launch_bounds__(256) void scan_addoff_kernel(int* __restrict__ data,
                                                          const int* __restrict__ boff,
                                                          int n_total) {
  int base = blockIdx.x * 1024 + threadIdx.x * 4;
  int add = boff[blockIdx.x];
#pragma unroll
  for (int j = 0; j < 4; ++j) {
    if (base + j < n_total) data[base + j] += add;
  }
}

// fused: scatter edges into CSR slots (i < E) + fill pad slots with dummy
// node N (i >= E covers node index i-E). Writes are disjoint; both depend
// only on row_ptr/deg.
__global__ __launch_bounds__(256) void fill_pad_kernel(const int* __restrict__ src,
                                                       const int* __restrict__ dst,
                                                       const int* __restrict__ row_ptr,
                                                       const int* __restrict__ deg,
                                                       int* __restrict__ cursor,
                                                       int* __restrict__ col, int E,
                                                       int n) {
  int i = blockIdx.x * 256 + threadIdx.x;
  if (i < E) {
    int d = dst[i];
    int p = atomicAdd(&cursor[d], 1);
    col[row_ptr[d] + p] = src[i];
  } else {
    int v = i - E;
    if (v < n) {
      int s = row_ptr[v] + deg[v];
      int e = row_ptr[v + 1];
#pragma unroll 1
      for (int j = s; j < e; ++j) col[j] = n;
    }
  }
}

// fused setup: graph_ptr from sorted batch (i <= n) + W1/W2 prep (i < 128*136)
// + dummy-node scores. All independent elementwise work.
__global__ __launch_bounds__(256) void setup_kernel(
    const int* __restrict__ batch, int* __restrict__ gp, int n, int G,
    const float* __restrict__ W1, const float* __restrict__ W2,
    unsigned short* __restrict__ wt1, unsigned short* __restrict__ wt2,
    float* __restrict__ asrc1, float* __restrict__ asrc2) {
  int i = blockIdx.x * 256 + threadIdx.x;
  if (i < n) {
    int prev = (i == 0) ? -1 : batch[i - 1];
    int cur = batch[i];
#pragma unroll 1
    for (int g = prev + 1; g <= cur; ++g) gp[g] = i;
  } else if (i == n) {
    int last = batch[n - 1];
#pragma unroll 1
    for (int g = last + 1; g <= G; ++g) gp[g] = n;
  }
  if (i < 128 * 136) {
    int nn = i / 136, k = i % 136;
    unsigned short z = 0;
    wt1[i] = (k < 128) ? f2bf(W1[(size_t)k * 128 + nn]) : z;
    wt2[i] = (k < 128) ? f2bf(W2[(size_t)k * 128 + nn]) : z;
  }
  if (i < 4) asrc1[(size_t)n * 4 + i] = -1e30f;
  if (i == 4) asrc2[n] = -1e30f;
}

// ---------------- MFMA GEMM + att-score epilogue (verified round 13) --------

template <int H, bool A_BF16>
__global__ __launch_bounds__(256) void gemm_att_mfma(
    const void* __restrict__ Av, const unsigned short* __restrict__ Wtp,
    const float* __restrict__ att_src, const float* __restrict__ att_dst,
    unsigned short* __restrict__ Cbf, float* __restrict__ asrc,
    float* __restrict__ adst) {
  __shared__ __align__(16) unsigned short Alds[64 * 136];
  __shared__ __align__(16) unsigned short Wlds[128 * 136];
  int tid = threadIdx.x;
  int lane = tid & 63;
  int wave = tid >> 6;
  int row0 = blockIdx.x * 64;

#pragma unroll
  for (int i = 0; i < 9; ++i) {
    int ch = tid + i * 256;
    if (ch < 2176) *(bf16x8*)&Wlds[ch * 8] = *(const bf16x8*)&Wtp[(size_t)ch * 8];
  }
#pragma unroll
  for (int i = 0; i < 4; ++i) {
    int ch = tid + i * 256;
    int r = ch >> 4, c = ch & 15;
    if constexpr (A_BF16) {
      bf16x8 v = *(const bf16x8*)((const unsigned short*)Av +
                                  (size_t)(row0 + r) * 128 + c * 8);
      *(bf16x8*)&Alds[r * 136 + c * 8] = v;
    } else {
      const float* A = (const float*)Av;
      float4 v0 = *(const float4*)(A + (size_t)(row0 + r) * 128 + c * 8);
      float4 v1 = *(const float4*)(A + (size_t)(row0 + r) * 128 + c * 8 + 4);
      unsigned short tmp[8] = {f2bf(v0.x), f2bf(v0.y), f2bf(v0.z), f2bf(v0.w),
                               f2bf(v1.x), f2bf(v1.y), f2bf(v1.z), f2bf(v1.w)};
      *(bf16x8*)&Alds[r * 136 + c * 8] = *(bf16x8*)tmp;
    }
  }
  __syncthreads();

  int l15 = lane & 15;
  int lg = lane >> 4;
  int wr = wave * 16;

  f32x4 acc[8];
#pragma unroll
  for (int nt = 0; nt < 8; ++nt) acc[nt] = (f32x4){0.f, 0.f, 0.f, 0.f};

#pragma unroll
  for (int ks = 0; ks < 4; ++ks) {
    bf16x8 af = *(const bf16x8*)&Alds[(wr + l15) * 136 + ks * 32 + lg * 8];
#pragma unroll
    for (int nt = 0; nt < 8; ++nt) {
      bf16x8 bfr = *(const bf16x8*)&Wlds[(nt * 16 + l15) * 136 + ks * 32 + lg * 8];
      acc[nt] = __builtin_amdgcn_mfma_f32_16x16x32_bf16(af, bfr, acc[nt], 0, 0, 0);
    }
  }

  float vsv[8], vdv[8];
#pragma unroll
  for (int nt = 0; nt < 8; ++nt) {
    vsv[nt] = att_src[nt * 16 + l15];
    vdv[nt] = att_dst[nt * 16 + l15];
  }

#pragma unroll
  for (int r = 0; r < 4; ++r) {
    int row = row0 + wr + lg * 4 + r;
#pragma unroll
    for (int nt = 0; nt < 8; ++nt) {
      Cbf[(size_t)row * 128 + nt * 16 + l15] = f2bf(acc[nt][r]);
    }
    if constexpr (H == 4) {
      float ps[4], pd[4];
#pragma unroll
      for (int hd = 0; hd < 4; ++hd) {
        ps[hd] = acc[2 * hd][r] * vsv[2 * hd] + acc[2 * hd + 1][r] * vsv[2 * hd + 1];
        pd[hd] = acc[2 * hd][r] * vdv[2 * hd] + acc[2 * hd + 1][r] * vdv[2 * hd + 1];
#pragma unroll
        for (int off = 1; off < 16; off <<= 1) {
          ps[hd] += __shfl_xor(ps[hd], off, 64);
          pd[hd] += __shfl_xor(pd[hd], off, 64);
        }
      }
      if (l15 < 4) {
        float pss = (l15 == 0) ? ps[0] : (l15 == 1) ? ps[1] : (l15 == 2) ? ps[2] : ps[3];
        float pds = (l15 == 0) ? pd[0] : (l15 == 1) ? pd[1] : (l15 == 2) ? pd[2] : pd[3];
        asrc[(size_t)row * 4 + l15] = pss;
        adst[(size_t)row * 4 + l15] = pds;
      }
    } else {
      float ps = 0.f, pd = 0.f;
#pragma unroll
      for (int nt = 0; nt < 8; ++nt) {
        ps = fmaf(acc[nt][r], vsv[nt], ps);
        pd = fmaf(acc[nt][r], vdv[nt], pd);
      }
#pragma unroll
      for (int off = 1; off < 16; off <<= 1) {
        ps += __shfl_xor(ps, off, 64);
        pd += __shfl_xor(pd, off, 64);
      }
      if (l15 == 0) {
        asrc[row] = ps;
        adst[row] = pd;
      }
    }
  }
}

// ---------------- Pass B: half-wave/node, grid-stride persistent waves ------
// Round-16 body (verified) wrapped in a grid-stride loop: waves stay resident
// and process ~12 node-pairs each, amortizing wave launch/drain (round-16 agg
// waves lived ~1-2 iterations; 100k waves/dispatch of churn).

template <int H, bool RELU, bool LNOUT>
__global__ __launch_bounds__(256) void gat_agg7_kernel(
    const unsigned short* __restrict__ h, const float* __restrict__ asrc,
    const float* __restrict__ adst, const int* __restrict__ row_ptr,
    const int* __restrict__ col, const float* __restrict__ bias,
    const float* __restrict__ gamma, const float* __restrict__ beta,
    unsigned short* __restrict__ outbf, int npairs, int n) {
  int gwave = (blockIdx.x * 256 + threadIdx.x) >> 6;
  int nwaves = gridDim.x * 4;
  int lane = threadIdx.x & 63;
  int half = lane >> 5;
  int cl = lane & 31;
  int c0 = cl * 4;
  const int hd = (H == 1) ? 0 : (cl >> 3);  // 32 channels per head

#pragma unroll 1
  for (int pair = gwave; pair < npairs; pair += nwaves) {
    int node = pair * 2 + half;  // n even -> always valid

    int e0 = row_ptr[node];
    int len = row_ptr[node + 1] - e0;  // padded to x4

    float ad = (H == 4) ? adst[(size_t)node * 4 + hd] : adst[node];
    float as_ = (H == 4) ? asrc[(size_t)node * 4 + hd] : asrc[node];
    float x = as_ + ad;
    x = (x > 0.f) ? x : NEG_SLOPE * x;
    float selfe = __expf(x);
    float den = selfe;

    float a0, a1, a2, a3;
    {
      uint2 hs = *(const uint2*)(h + (size_t)node * 128 + c0);
      a0 = bfu_lo(hs.x) * selfe;
      a1 = bfu_hi(hs.x) * selfe;
      a2 = bfu_lo(hs.y) * selfe;
      a3 = bfu_hi(hs.y) * selfe;
    }

#pragma unroll 1
    for (int t = 0; t < len; t += 4) {
      int4 s4 = *(const int4*)(col + e0 + t);  // 16B aligned
      float sc0, sc1, sc2, sc3;
      if constexpr (H == 4) {
        sc0 = asrc[(size_t)s4.x * 4 + hd];
        sc1 = asrc[(size_t)s4.y * 4 + hd];
        sc2 = asrc[(size_t)s4.z * 4 + hd];
        sc3 = asrc[(size_t)s4.w * 4 + hd];
      } else {
        sc0 = asrc[s4.x];
        sc1 = asrc[s4.y];
        sc2 = asrc[s4.z];
        sc3 = asrc[s4.w];
      }
      uint2 h0 = *(const uint2*)(h + (size_t)s4.x * 128 + c0);
      uint2 h1 = *(const uint2*)(h + (size_t)s4.y * 128 + c0);
      uint2 h2 = *(const uint2*)(h + (size_t)s4.z * 128 + c0);
      uint2 h3 = *(const uint2*)(h + (size_t)s4.w * 128 + c0);

      float y0 = sc0 + ad; y0 = (y0 > 0.f) ? y0 : NEG_SLOPE * y0;
      float e0f = __expf(y0);
      float y1 = sc1 + ad; y1 = (y1 > 0.f) ? y1 : NEG_SLOPE * y1;
      float e1f = __expf(y1);
      float y2 = sc2 + ad; y2 = (y2 > 0.f) ? y2 : NEG_SLOPE * y2;
      float e2f = __expf(y2);
      float y3 = sc3 + ad; y3 = (y3 > 0.f) ? y3 : NEG_SLOPE * y3;
      float e3f = __expf(y3);
      den += e0f + e1f + e2f + e3f;

      a0 = fmaf(bfu_lo(h0.x), e0f, a0);
      a1 = fmaf(bfu_hi(h0.x), e0f, a1);
      a2 = fmaf(bfu_lo(h0.y), e0f, a2);
      a3 = fmaf(bfu_hi(h0.y), e0f, a3);
      a0 = fmaf(bfu_lo(h1.x), e1f, a0);
      a1 = fmaf(bfu_hi(h1.x), e1f, a1);
      a2 = fmaf(bfu_lo(h1.y), e1f, a2);
      a3 = fmaf(bfu_hi(h1.y), e1f, a3);
      a0 = fmaf(bfu_lo(h2.x), e2f, a0);
      a1 = fmaf(bfu_hi(h2.x), e2f, a1);
      a2 = fmaf(bfu_lo(h2.y), e2f, a2);
      a3 = fmaf(bfu_hi(h2.y), e2f, a3);
      a0 = fmaf(bfu_lo(h3.x), e3f, a0);
      a1 = fmaf(bfu_hi(h3.x), e3f, a1);
      a2 = fmaf(bfu_lo(h3.y), e3f, a2);
      a3 = fmaf(bfu_hi(h3.y), e3f, a3);
    }

    float inv = 1.f / den;
    float4 b4 = *(const float4*)(bias + c0);
    float o0 = fmaf(a0, inv, b4.x);
    float o1 = fmaf(a1, inv, b4.y);
    float o2 = fmaf(a2, inv, b4.z);
    float o3 = fmaf(a3, inv, b4.w);
    if (RELU) {
      o0 = fmaxf(o0, 0.f);
      o1 = fmaxf(o1, 0.f);
      o2 = fmaxf(o2, 0.f);
      o3 = fmaxf(o3, 0.f);
    }

    if (!LNOUT) {
      uint2 pv;
      pv.x = (unsigned)f2bf(o0) | ((unsigned)f2bf(o1) << 16);
      pv.y = (unsigned)f2bf(o2) | ((unsigned)f2bf(o3) << 16);
      *(uint2*)(outbf + (size_t)node * 128 + c0) = pv;
    } else {
      // LayerNorm over 128 channels held by the 32-lane half (4/lane)
      float ssum = o0 + o1 + o2 + o3;
#pragma unroll
      for (int off = 1; off < 32; off <<= 1) ssum += __shfl_xor(ssum, off, 64);
      float mu = ssum * (1.f / 128.f);
      float d0 = o0 - mu, d1 = o1 - mu, d2 = o2 - mu, d3 = o3 - mu;
      float vs2 = d0 * d0 + d1 * d1 + d2 * d2 + d3 * d3;
#pragma unroll
      for (int off = 1; off < 32; off <<= 1) vs2 += __shfl_xor(vs2, off, 64);
      float ivn = rsqrtf(vs2 * (1.f / 128.f) + LN_EPS);
      float4 g4 = *(const float4*)(gamma + c0);
      float4 be4 = *(const float4*)(beta + c0);
      float q0 = fmaf(d0 * ivn, g4.x, be4.x);
      float q1 = fmaf(d1 * ivn, g4.y, be4.y);
      float q2 = fmaf(d2 * ivn, g4.z, be4.z);
      float q3 = fmaf(d3 * ivn, g4.w, be4.w);
      uint2 pv;
      pv.x = (unsigned)f2bf(q0) | ((unsigned)f2bf(q1) << 16);
      pv.y = (unsigned)f2bf(q2) | ((unsigned)f2bf(q3) << 16);
      *(uint2*)(outbf + (size_t)node * 128 + c0) = pv;
    }
  }
}

// ---------------- mean pool: one wave per graph, contiguous rows -------------

__global__ __launch_bounds__(256) void pool_kernel(const unsigned short* __restrict__ hln,
                                                   const int* __restrict__ gp,
                                                   float* __restrict__ out, int G) {
  int g = (blockIdx.x * 256 + threadIdx.x) >> 6;
  int lane = threadIdx.x & 63;
  if (g >= G) return;
  int s = gp[g], e = gp[g + 1];
  float ax = 0.f, ay = 0.f;
#pragma unroll 1
  for (int i = s; i < e; ++i) {
    unsigned v = *(const unsigned*)(hln + (size_t)i * 128 + lane * 2);
    ax += bfu_lo(v);
    ay += bfu_hi(v);
  }
  int c = e - s;
  float sc = 1.f / (float)((c > 0) ? c : 1);
  *(float2*)(out + (size_t)g * 128 + lane * 2) = make_float2(ax * sc, ay * sc);
}

// ---------------- launch ----------------

extern "C" void kernel_launch(void* const* d_in, const int* in_sizes, int n_in,
                              void* d_out, int out_size, void* d_ws, size_t ws_size,
                              hipStream_t stream) {
  const float* x = (const float*)d_in[0];
  const int* ei = (const int*)d_in[1];
  const int* batch = (const int*)d_in[2];
  const float* W1 = (const float*)d_in[3];
  const float* att_src1 = (const float*)d_in[4];
  const float* att_dst1 = (const float*)d_in[5];
  const float* b1 = (const float*)d_in[6];
  const float* W2 = (const float*)d_in[7];
  const float* att_src2 = (const float*)d_in[8];
  const float* att_dst2 = (const float*)d_in[9];
  const float* b2 = (const float*)d_in[10];
  const float* gamma = (const float*)d_in[11];
  const float* beta = (const float*)d_in[12];
  float* out = (float*)d_out;

  const int N = N_NODES_C, E = N_EDGES_C, G = NUM_GRAPHS_C;
  const int COLSZ = E + 3 * N + 16;  // padded CSR upper bound (pad <= 3/row)
  const int* src = ei;
  const int* dst = ei + E;

  float* p = (float*)d_ws;
  float* asrc1 = p; p += (size_t)(N + 1) * 4;  // +dummy row (asrc[N]=-1e30)
  float* adst1 = p; p += (size_t)N * 4;
  float* asrc2 = p; p += N + 1;
  float* adst2 = p; p += N;
  int* ip = (int*)p;
  int* deg = ip;       ip += N + 1;  // deg[N]=0; adjacent to cursor (one memset)
  int* cursor = ip;    ip += N;
  int* col = ip;       ip += COLSZ;
  int* bsums = ip;     ip += 256;
  int* bsums2 = ip;    ip += 256;
  int* row_ptr = ip;   ip += N + 2;
  int* graph_ptr = ip; ip += G + 2;
  unsigned short* h1bf = (unsigned short*)ip;          // [(N+1)*128] bf16 (+dummy row)
  unsigned short* hbbf = h1bf + (size_t)(N + 1) * 128;
  unsigned short* h2bf = hbbf + (size_t)(N + 1) * 128;
  unsigned short* wt1 = h2bf + (size_t)(N + 1) * 128;  // [128*136] bf16 W^T padded
  unsigned short* wt2 = wt1 + 128 * 136;
  (void)ws_size; (void)in_sizes; (void)n_in; (void)out_size;

  // deg (N+1) and cursor (N) are adjacent: single memset
  hipMemsetAsync(deg, 0, sizeof(int) * (size_t)(2 * N + 1), stream);

  // CSR (rows padded to x4) + fused setup (graph_ptr, W prep, dummy scores)
  count_deg_kernel<<<(E + 255) / 256, 256, 0, stream>>>(dst, deg, E);
  int nblk = (N + 1 + 1023) / 1024;
  scan_kernel<<<nblk, 256, 0, stream>>>(deg, row_ptr, bsums, N + 1, N);
  scan_kernel<<<1, 256, 0, stream>>>(bsums, bsums2, nullptr, nblk, 0);
  scan_addoff_kernel<<<nblk, 256, 0, stream>>>(row_ptr, bsums2, N + 1);
  fill_pad_kernel<<<(E + N + 255) / 256, 256, 0, stream>>>(src, dst, row_ptr, deg,
                                                           cursor, col, E, N);
  setup_kernel<<<(N + 1 + 255) / 256, 256, 0, stream>>>(
      batch, graph_ptr, N, G, W1, W2, wt1, wt2, asrc1, asrc2);

  int npairs = N / 2;    // N even
  int ablocks = 2048;    // grid-stride persistent waves (~12 pairs/wave)
  int gblocks = N / 64;  // 200000 = 64*3125 exactly

  // Layer 1: GAT(128 -> 4x32), ReLU
  gemm_att_mfma<4, false><<<gblocks, 256, 0, stream>>>(
      x, wt1, att_src1, att_dst1, h1bf, asrc1, adst1);
  gat_agg7_kernel<4, true, false><<<ablocks, 256, 0, stream>>>(
      h1bf, asrc1, adst1, row_ptr, col, b1, nullptr, nullptr, hbbf, npairs, N);

  // Layer 2: GAT(128 -> 1x128) + fused LayerNorm -> bf16 rows
  gemm_att_mfma<1, true><<<gblocks, 256, 0, stream>>>(
      hbbf, wt2, att_src2, att_dst2, h2bf, asrc2, adst2);
  gat_agg7_kernel<1, false, true><<<ablocks, 256, 0, stream>>>(
      h2bf, asrc2, adst2, row_ptr, col, b2, gamma, beta, h1bf, npairs, N);

  // mean pool per graph: contiguous segmented reduction -> d_out
  pool_kernel<<<(int)(((size_t)G * 64 + 255) / 256), 256, 0, stream>>>(
      h1bf, graph_ptr, out, G);
}

// Round 18
// 286.640 us; speedup vs baseline: 1.1972x; 1.0233x over previous
//
#include <hip/hip_runtime.h>
#include <cstdint>
#include <cstddef>

#define N_NODES_C 200000
#define N_EDGES_C 600000
#define NUM_GRAPHS_C 20000

constexpr float NEG_SLOPE = 0.2f;
constexpr float LN_EPS = 1e-5f;

typedef __attribute__((ext_vector_type(8))) short bf16x8;
typedef __attribute__((ext_vector_type(4))) float f32x4;

// bf16 helpers (RNE)
static __device__ __forceinline__ unsigned short f2bf(float f) {
  unsigned u = __float_as_uint(f);
  u = (u + 0x7fffu + ((u >> 16) & 1u)) >> 16;
  return (unsigned short)u;
}
static __device__ __forceinline__ float bf2f(unsigned short s) {
  return __uint_as_float(((unsigned)s) << 16);
}
// unpack packed pair of bf16 from a dword (1 VALU each)
static __device__ __forceinline__ float bfu_lo(unsigned u) {
  return __uint_as_float(u << 16);
}
static __device__ __forceinline__ float bfu_hi(unsigned u) {
  return __uint_as_float(u & 0xffff0000u);
}

// ---------------- CSR build ----------------

__global__ __launch_bounds__(256) void count_deg_kernel(const int* __restrict__ dst,
                                                        int* __restrict__ deg, int E) {
  int e = blockIdx.x * 256 + threadIdx.x;
  if (e < E) atomicAdd(&deg[dst[e]], 1);
}

// exclusive scan over n_total elements; elements with idx < npad are
// transformed deg -> ceil(deg/4)*4 (pad rows to x4; no extra dummy block).
__global__ __launch_bounds__(256) void scan_kernel(const int* __restrict__ in,
                                                   int* __restrict__ out,
                                                   int* __restrict__ bsums,
                                                   int n_total, int npad) {
  __shared__ int ss[256];
  int t = threadIdx.x;
  int base = blockIdx.x * 1024 + t * 4;
  int v[4];
  int s = 0;
#pragma unroll
  for (int j = 0; j < 4; ++j) {
    int idx = base + j;
    int x = (idx < n_total) ? in[idx] : 0;
    if (idx < npad) x = (x + 3) & ~3;
    v[j] = x;
    s += x;
  }
  ss[t] = s;
  __syncthreads();
  for (int off = 1; off < 256; off <<= 1) {
    int x = (t >= off) ? ss[t - off] : 0;
    __syncthreads();
    ss[t] += x;
    __syncthreads();
  }
  int incl = ss[t];
  int excl = incl - s;
  if (bsums != nullptr && t == 255) bsums[blockIdx.x] = incl;
  int run = excl;
#pragma unroll
  for (int j = 0; j < 4; ++j) {
    if (base + j < n_total) out[base + j] = run;
    run += v[j];
  }
}

__global__ __launch_bounds__(256) void scan_addoff_kernel(int* __restrict__ data,
                                                          const int* __restrict__ boff,
                                                          int n_total) {
  int base = blockIdx.x * 1024 + threadIdx.x * 4;
  int add = boff[blockIdx.x];
#pragma unroll
  for (int j = 0; j < 4; ++j) {
    if (base + j < n_total) data[base + j] += add;
  }
}

// fused: scatter edges into CSR slots (i < E) + fill pad slots with dummy
// node N (i >= E covers node index i-E). Writes are disjoint.
__global__ __launch_bounds__(256) void fill_pad_kernel(const int* __restrict__ src,
                                                       const int* __restrict__ dst,
                                                       const int* __restrict__ row_ptr,
                                                       const int* __restrict__ deg,
                                                       int* __restrict__ cursor,
                                                       int* __restrict__ col, int E,
                                                       int n) {
  int i = blockIdx.x * 256 + threadIdx.x;
  if (i < E) {
    int d = dst[i];
    int p = atomicAdd(&cursor[d], 1);
    col[row_ptr[d] + p] = src[i];
  } else {
    int v = i - E;
    if (v < n) {
      int s = row_ptr[v] + deg[v];
      int e = row_ptr[v + 1];
#pragma unroll 1
      for (int j = s; j < e; ++j) col[j] = n;
    }
  }
}

// fused setup: graph_ptr from sorted batch (i <= n) + W1/W2 prep (i < 128*136)
// + dummy-node scores. All independent elementwise work.
__global__ __launch_bounds__(256) void setup_kernel(
    const int* __restrict__ batch, int* __restrict__ gp, int n, int G,
    const float* __restrict__ W1, const float* __restrict__ W2,
    unsigned short* __restrict__ wt1, unsigned short* __restrict__ wt2,
    float* __restrict__ asrc1, float* __restrict__ asrc2) {
  int i = blockIdx.x * 256 + threadIdx.x;
  if (i < n) {
    int prev = (i == 0) ? -1 : batch[i - 1];
    int cur = batch[i];
#pragma unroll 1
    for (int g = prev + 1; g <= cur; ++g) gp[g] = i;
  } else if (i == n) {
    int last = batch[n - 1];
#pragma unroll 1
    for (int g = last + 1; g <= G; ++g) gp[g] = n;
  }
  if (i < 128 * 136) {
    int nn = i / 136, k = i % 136;
    unsigned short z = 0;
    wt1[i] = (k < 128) ? f2bf(W1[(size_t)k * 128 + nn]) : z;
    wt2[i] = (k < 128) ? f2bf(W2[(size_t)k * 128 + nn]) : z;
  }
  if (i < 4) asrc1[(size_t)n * 4 + i] = -1e30f;
  if (i == 4) asrc2[n] = -1e30f;
}

// ---------------- MFMA GEMM + att-score epilogue (verified round 13) --------

template <int H, bool A_BF16>
__global__ __launch_bounds__(256) void gemm_att_mfma(
    const void* __restrict__ Av, const unsigned short* __restrict__ Wtp,
    const float* __restrict__ att_src, const float* __restrict__ att_dst,
    unsigned short* __restrict__ Cbf, float* __restrict__ asrc,
    float* __restrict__ adst) {
  __shared__ __align__(16) unsigned short Alds[64 * 136];
  __shared__ __align__(16) unsigned short Wlds[128 * 136];
  int tid = threadIdx.x;
  int lane = tid & 63;
  int wave = tid >> 6;
  int row0 = blockIdx.x * 64;

#pragma unroll
  for (int i = 0; i < 9; ++i) {
    int ch = tid + i * 256;
    if (ch < 2176) *(bf16x8*)&Wlds[ch * 8] = *(const bf16x8*)&Wtp[(size_t)ch * 8];
  }
#pragma unroll
  for (int i = 0; i < 4; ++i) {
    int ch = tid + i * 256;
    int r = ch >> 4, c = ch & 15;
    if constexpr (A_BF16) {
      bf16x8 v = *(const bf16x8*)((const unsigned short*)Av +
                                  (size_t)(row0 + r) * 128 + c * 8);
      *(bf16x8*)&Alds[r * 136 + c * 8] = v;
    } else {
      const float* A = (const float*)Av;
      float4 v0 = *(const float4*)(A + (size_t)(row0 + r) * 128 + c * 8);
      float4 v1 = *(const float4*)(A + (size_t)(row0 + r) * 128 + c * 8 + 4);
      unsigned short tmp[8] = {f2bf(v0.x), f2bf(v0.y), f2bf(v0.z), f2bf(v0.w),
                               f2bf(v1.x), f2bf(v1.y), f2bf(v1.z), f2bf(v1.w)};
      *(bf16x8*)&Alds[r * 136 + c * 8] = *(bf16x8*)tmp;
    }
  }
  __syncthreads();

  int l15 = lane & 15;
  int lg = lane >> 4;
  int wr = wave * 16;

  f32x4 acc[8];
#pragma unroll
  for (int nt = 0; nt < 8; ++nt) acc[nt] = (f32x4){0.f, 0.f, 0.f, 0.f};

#pragma unroll
  for (int ks = 0; ks < 4; ++ks) {
    bf16x8 af = *(const bf16x8*)&Alds[(wr + l15) * 136 + ks * 32 + lg * 8];
#pragma unroll
    for (int nt = 0; nt < 8; ++nt) {
      bf16x8 bfr = *(const bf16x8*)&Wlds[(nt * 16 + l15) * 136 + ks * 32 + lg * 8];
      acc[nt] = __builtin_amdgcn_mfma_f32_16x16x32_bf16(af, bfr, acc[nt], 0, 0, 0);
    }
  }

  float vsv[8], vdv[8];
#pragma unroll
  for (int nt = 0; nt < 8; ++nt) {
    vsv[nt] = att_src[nt * 16 + l15];
    vdv[nt] = att_dst[nt * 16 + l15];
  }

#pragma unroll
  for (int r = 0; r < 4; ++r) {
    int row = row0 + wr + lg * 4 + r;
#pragma unroll
    for (int nt = 0; nt < 8; ++nt) {
      Cbf[(size_t)row * 128 + nt * 16 + l15] = f2bf(acc[nt][r]);
    }
    if constexpr (H == 4) {
      float ps[4], pd[4];
#pragma unroll
      for (int hd = 0; hd < 4; ++hd) {
        ps[hd] = acc[2 * hd][r] * vsv[2 * hd] + acc[2 * hd + 1][r] * vsv[2 * hd + 1];
        pd[hd] = acc[2 * hd][r] * vdv[2 * hd] + acc[2 * hd + 1][r] * vdv[2 * hd + 1];
#pragma unroll
        for (int off = 1; off < 16; off <<= 1) {
          ps[hd] += __shfl_xor(ps[hd], off, 64);
          pd[hd] += __shfl_xor(pd[hd], off, 64);
        }
      }
      if (l15 < 4) {
        float pss = (l15 == 0) ? ps[0] : (l15 == 1) ? ps[1] : (l15 == 2) ? ps[2] : ps[3];
        float pds = (l15 == 0) ? pd[0] : (l15 == 1) ? pd[1] : (l15 == 2) ? pd[2] : pd[3];
        asrc[(size_t)row * 4 + l15] = pss;
        adst[(size_t)row * 4 + l15] = pds;
      }
    } else {
      float ps = 0.f, pd = 0.f;
#pragma unroll
      for (int nt = 0; nt < 8; ++nt) {
        ps = fmaf(acc[nt][r], vsv[nt], ps);
        pd = fmaf(acc[nt][r], vdv[nt], pd);
      }
#pragma unroll
      for (int off = 1; off < 16; off <<= 1) {
        ps += __shfl_xor(ps, off, 64);
        pd += __shfl_xor(pd, off, 64);
      }
      if (l15 == 0) {
        asrc[row] = ps;
        adst[row] = pd;
      }
    }
  }
}

// ---------------- Pass B: half-wave per node, one pair per wave (round 16) --
// Round-17 lesson: persistent grid-stride REGRESSED (61 -> 65 us) — 100k
// short waves give the scheduler more inter-node MLP than 8k waves serially
// walking pairs. Keep one node-pair per wave.

template <int H, bool RELU, bool LNOUT>
__global__ __launch_bounds__(256) void gat_agg6_kernel(
    const unsigned short* __restrict__ h, const float* __restrict__ asrc,
    const float* __restrict__ adst, const int* __restrict__ row_ptr,
    const int* __restrict__ col, const float* __restrict__ bias,
    const float* __restrict__ gamma, const float* __restrict__ beta,
    unsigned short* __restrict__ outbf, int n) {
  int wid = (blockIdx.x * 256 + threadIdx.x) >> 6;
  int lane = threadIdx.x & 63;
  int half = lane >> 5;
  int cl = lane & 31;
  int node = wid * 2 + half;  // n even -> wave-uniform validity
  if (node >= n) return;

  int e0 = row_ptr[node];
  int len = row_ptr[node + 1] - e0;  // padded to x4
  int c0 = cl * 4;
  const int hd = (H == 1) ? 0 : (cl >> 3);  // 32 channels per head

  float ad = (H == 4) ? adst[(size_t)node * 4 + hd] : adst[node];
  float as_ = (H == 4) ? asrc[(size_t)node * 4 + hd] : asrc[node];
  float x = as_ + ad;
  x = (x > 0.f) ? x : NEG_SLOPE * x;
  float selfe = __expf(x);
  float den = selfe;

  float a0, a1, a2, a3;
  {
    uint2 hs = *(const uint2*)(h + (size_t)node * 128 + c0);
    a0 = bfu_lo(hs.x) * selfe;
    a1 = bfu_hi(hs.x) * selfe;
    a2 = bfu_lo(hs.y) * selfe;
    a3 = bfu_hi(hs.y) * selfe;
  }

#pragma unroll 1
  for (int t = 0; t < len; t += 4) {
    int4 s4 = *(const int4*)(col + e0 + t);  // 16B aligned
    float sc0, sc1, sc2, sc3;
    if constexpr (H == 4) {
      sc0 = asrc[(size_t)s4.x * 4 + hd];
      sc1 = asrc[(size_t)s4.y * 4 + hd];
      sc2 = asrc[(size_t)s4.z * 4 + hd];
      sc3 = asrc[(size_t)s4.w * 4 + hd];
    } else {
      sc0 = asrc[s4.x];
      sc1 = asrc[s4.y];
      sc2 = asrc[s4.z];
      sc3 = asrc[s4.w];
    }
    uint2 h0 = *(const uint2*)(h + (size_t)s4.x * 128 + c0);
    uint2 h1 = *(const uint2*)(h + (size_t)s4.y * 128 + c0);
    uint2 h2 = *(const uint2*)(h + (size_t)s4.z * 128 + c0);
    uint2 h3 = *(const uint2*)(h + (size_t)s4.w * 128 + c0);

    float y0 = sc0 + ad; y0 = (y0 > 0.f) ? y0 : NEG_SLOPE * y0;
    float e0f = __expf(y0);
    float y1 = sc1 + ad; y1 = (y1 > 0.f) ? y1 : NEG_SLOPE * y1;
    float e1f = __expf(y1);
    float y2 = sc2 + ad; y2 = (y2 > 0.f) ? y2 : NEG_SLOPE * y2;
    float e2f = __expf(y2);
    float y3 = sc3 + ad; y3 = (y3 > 0.f) ? y3 : NEG_SLOPE * y3;
    float e3f = __expf(y3);
    den += e0f + e1f + e2f + e3f;

    a0 = fmaf(bfu_lo(h0.x), e0f, a0);
    a1 = fmaf(bfu_hi(h0.x), e0f, a1);
    a2 = fmaf(bfu_lo(h0.y), e0f, a2);
    a3 = fmaf(bfu_hi(h0.y), e0f, a3);
    a0 = fmaf(bfu_lo(h1.x), e1f, a0);
    a1 = fmaf(bfu_hi(h1.x), e1f, a1);
    a2 = fmaf(bfu_lo(h1.y), e1f, a2);
    a3 = fmaf(bfu_hi(h1.y), e1f, a3);
    a0 = fmaf(bfu_lo(h2.x), e2f, a0);
    a1 = fmaf(bfu_hi(h2.x), e2f, a1);
    a2 = fmaf(bfu_lo(h2.y), e2f, a2);
    a3 = fmaf(bfu_hi(h2.y), e2f, a3);
    a0 = fmaf(bfu_lo(h3.x), e3f, a0);
    a1 = fmaf(bfu_hi(h3.x), e3f, a1);
    a2 = fmaf(bfu_lo(h3.y), e3f, a2);
    a3 = fmaf(bfu_hi(h3.y), e3f, a3);
  }

  float inv = 1.f / den;
  float4 b4 = *(const float4*)(bias + c0);
  float o0 = fmaf(a0, inv, b4.x);
  float o1 = fmaf(a1, inv, b4.y);
  float o2 = fmaf(a2, inv, b4.z);
  float o3 = fmaf(a3, inv, b4.w);
  if (RELU) {
    o0 = fmaxf(o0, 0.f);
    o1 = fmaxf(o1, 0.f);
    o2 = fmaxf(o2, 0.f);
    o3 = fmaxf(o3, 0.f);
  }

  if (!LNOUT) {
    uint2 pv;
    pv.x = (unsigned)f2bf(o0) | ((unsigned)f2bf(o1) << 16);
    pv.y = (unsigned)f2bf(o2) | ((unsigned)f2bf(o3) << 16);
    *(uint2*)(outbf + (size_t)node * 128 + c0) = pv;
  } else {
    // LayerNorm over 128 channels held by the 32-lane half (4/lane);
    // shfl_xor offsets 1..16 stay within the half (bit5 preserved).
    float ssum = o0 + o1 + o2 + o3;
#pragma unroll
    for (int off = 1; off < 32; off <<= 1) ssum += __shfl_xor(ssum, off, 64);
    float mu = ssum * (1.f / 128.f);
    float d0 = o0 - mu, d1 = o1 - mu, d2 = o2 - mu, d3 = o3 - mu;
    float vs2 = d0 * d0 + d1 * d1 + d2 * d2 + d3 * d3;
#pragma unroll
    for (int off = 1; off < 32; off <<= 1) vs2 += __shfl_xor(vs2, off, 64);
    float ivn = rsqrtf(vs2 * (1.f / 128.f) + LN_EPS);
    float4 g4 = *(const float4*)(gamma + c0);
    float4 be4 = *(const float4*)(beta + c0);
    float q0 = fmaf(d0 * ivn, g4.x, be4.x);
    float q1 = fmaf(d1 * ivn, g4.y, be4.y);
    float q2 = fmaf(d2 * ivn, g4.z, be4.z);
    float q3 = fmaf(d3 * ivn, g4.w, be4.w);
    uint2 pv;
    pv.x = (unsigned)f2bf(q0) | ((unsigned)f2bf(q1) << 16);
    pv.y = (unsigned)f2bf(q2) | ((unsigned)f2bf(q3) << 16);
    *(uint2*)(outbf + (size_t)node * 128 + c0) = pv;
  }
}

// ---------------- mean pool: one wave per graph, contiguous rows -------------

__global__ __launch_bounds__(256) void pool_kernel(const unsigned short* __restrict__ hln,
                                                   const int* __restrict__ gp,
                                                   float* __restrict__ out, int G) {
  int g = (blockIdx.x * 256 + threadIdx.x) >> 6;
  int lane = threadIdx.x & 63;
  if (g >= G) return;
  int s = gp[g], e = gp[g + 1];
  float ax = 0.f, ay = 0.f;
#pragma unroll 1
  for (int i = s; i < e; ++i) {
    unsigned v = *(const unsigned*)(hln + (size_t)i * 128 + lane * 2);
    ax += bfu_lo(v);
    ay += bfu_hi(v);
  }
  int c = e - s;
  float sc = 1.f / (float)((c > 0) ? c : 1);
  *(float2*)(out + (size_t)g * 128 + lane * 2) = make_float2(ax * sc, ay * sc);
}

// ---------------- launch ----------------

extern "C" void kernel_launch(void* const* d_in, const int* in_sizes, int n_in,
                              void* d_out, int out_size, void* d_ws, size_t ws_size,
                              hipStream_t stream) {
  const float* x = (const float*)d_in[0];
  const int* ei = (const int*)d_in[1];
  const int* batch = (const int*)d_in[2];
  const float* W1 = (const float*)d_in[3];
  const float* att_src1 = (const float*)d_in[4];
  const float* att_dst1 = (const float*)d_in[5];
  const float* b1 = (const float*)d_in[6];
  const float* W2 = (const float*)d_in[7];
  const float* att_src2 = (const float*)d_in[8];
  const float* att_dst2 = (const float*)d_in[9];
  const float* b2 = (const float*)d_in[10];
  const float* gamma = (const float*)d_in[11];
  const float* beta = (const float*)d_in[12];
  float* out = (float*)d_out;

  const int N = N_NODES_C, E = N_EDGES_C, G = NUM_GRAPHS_C;
  const int COLSZ = E + 3 * N + 16;  // padded CSR upper bound (pad <= 3/row)
  const int* src = ei;
  const int* dst = ei + E;

  float* p = (float*)d_ws;
  float* asrc1 = p; p += (size_t)(N + 1) * 4;  // +dummy row (asrc[N]=-1e30)
  float* adst1 = p; p += (size_t)N * 4;
  float* asrc2 = p; p += N + 1;
  float* adst2 = p; p += N;
  int* ip = (int*)p;
  int* deg = ip;       ip += N + 1;  // deg[N]=0; adjacent to cursor (one memset)
  int* cursor = ip;    ip += N;
  int* col = ip;       ip += COLSZ;
  int* bsums = ip;     ip += 256;
  int* bsums2 = ip;    ip += 256;
  int* row_ptr = ip;   ip += N + 2;
  int* graph_ptr = ip; ip += G + 2;
  unsigned short* h1bf = (unsigned short*)ip;          // [(N+1)*128] bf16 (+dummy row)
  unsigned short* hbbf = h1bf + (size_t)(N + 1) * 128;
  unsigned short* h2bf = hbbf + (size_t)(N + 1) * 128;
  unsigned short* wt1 = h2bf + (size_t)(N + 1) * 128;  // [128*136] bf16 W^T padded
  unsigned short* wt2 = wt1 + 128 * 136;
  (void)ws_size; (void)in_sizes; (void)n_in; (void)out_size;

  // deg (N+1) and cursor (N) are adjacent: single memset
  hipMemsetAsync(deg, 0, sizeof(int) * (size_t)(2 * N + 1), stream);

  // CSR (rows padded to x4) + fused setup (graph_ptr, W prep, dummy scores)
  count_deg_kernel<<<(E + 255) / 256, 256, 0, stream>>>(dst, deg, E);
  int nblk = (N + 1 + 1023) / 1024;
  scan_kernel<<<nblk, 256, 0, stream>>>(deg, row_ptr, bsums, N + 1, N);
  scan_kernel<<<1, 256, 0, stream>>>(bsums, bsums2, nullptr, nblk, 0);
  scan_addoff_kernel<<<nblk, 256, 0, stream>>>(row_ptr, bsums2, N + 1);
  fill_pad_kernel<<<(E + N + 255) / 256, 256, 0, stream>>>(src, dst, row_ptr, deg,
                                                           cursor, col, E, N);
  setup_kernel<<<(N + 1 + 255) / 256, 256, 0, stream>>>(
      batch, graph_ptr, N, G, W1, W2, wt1, wt2, asrc1, asrc2);

  int pblocks = N / 8;   // 2 nodes/wave, 4 waves/block; 200000/8 exact
  int gblocks = N / 64;  // 200000 = 64*3125 exactly

  // Layer 1: GAT(128 -> 4x32), ReLU
  gemm_att_mfma<4, false><<<gblocks, 256, 0, stream>>>(
      x, wt1, att_src1, att_dst1, h1bf, asrc1, adst1);
  gat_agg6_kernel<4, true, false><<<pblocks, 256, 0, stream>>>(
      h1bf, asrc1, adst1, row_ptr, col, b1, nullptr, nullptr, hbbf, N);

  // Layer 2: GAT(128 -> 1x128) + fused LayerNorm -> bf16 rows
  gemm_att_mfma<1, true><<<gblocks, 256, 0, stream>>>(
      hbbf, wt2, att_src2, att_dst2, h2bf, asrc2, adst2);
  gat_agg6_kernel<1, false, true><<<pblocks, 256, 0, stream>>>(
      h2bf, asrc2, adst2, row_ptr, col, b2, gamma, beta, h1bf, N);

  // mean pool per graph: contiguous segmented reduction -> d_out
  pool_kernel<<<(int)(((size_t)G * 64 + 255) / 256), 256, 0, stream>>>(
      h1bf, graph_ptr, out, G);
}